// Round 11
// baseline (450.500 us; speedup 1.0000x reference)
//
#include <hip/hip_runtime.h>

// ---------------- problem constants ----------------
#define T_TOK 16384
#define DM    512
#define DFF   2048
#define NE    8
#define NP    16
#define KP    4
#define RANK  64
#define KR    256           // KP * RANK
#define EPSF  1e-8f
#define CAP   6144          // per-expert pair capacity (expected ~4096)
#define MT_E  48            // CAP / 128 M-tiles per expert

typedef unsigned short u16;
typedef __bf16 bf16x8 __attribute__((ext_vector_type(8)));
typedef float  f32x4  __attribute__((ext_vector_type(4)));
typedef unsigned short u16x8v __attribute__((ext_vector_type(8)));
typedef unsigned short u16x4v __attribute__((ext_vector_type(4)));

typedef __attribute__((address_space(3))) void as3_void;
typedef __attribute__((address_space(1))) void as1_void;

__device__ __forceinline__ u16 f2bf(float f) {
  return __builtin_bit_cast(u16, (__bf16)f);    // native RTNE cvt (R7)
}
__device__ __forceinline__ float bf2f(u16 v) {
  unsigned int u = ((unsigned int)v) << 16;
  return __builtin_bit_cast(float, u);
}

__device__ __forceinline__ void gl_lds16(const u16* g, u16* l) {
  __builtin_amdgcn_global_load_lds((as1_void*)g, (as3_void*)l, 16, 0, 0);
}

// ---- 3-bit XOR swizzle for 64-col (128 B row-stride) LDS tiles ----
// granule' = granule ^ (row&7); readers XOR col with ((row&7)<<3) == per-lane
// (ln&7)<<3. (R6: st_16x32 1-bit variant is WRONG for this layout.)

// stage 128x64 bf16 tile into LDS, source pre-swizzled (gl_lds dst linear)
__device__ __forceinline__ void stage_tile(const u16* g, int ld, u16* lds_tile, int tid) {
  int row = tid >> 3, cc = tid & 7;
#pragma unroll
  for (int ri = 0; ri < 4; ri++) {
    int rg = ri * 32 + row;
    gl_lds16(g + (size_t)rg * ld + ((cc ^ (rg & 7)) * 8), &lds_tile[rg * 64 + cc * 8]);
  }
}

// ---------------- zero counters ----------------
__global__ void zero_kernel(int* __restrict__ cnt, float* __restrict__ probsum) {
  int i = blockIdx.x * 256 + threadIdx.x;
  if (i < NE) cnt[i] = 0;
  if (i >= NE && i < NE + NE * 64) probsum[i - NE] = 0.f;
}

// ---------------- primitive-bank softmax + top-4 ----------------
__global__ void compose_meta(const float* __restrict__ fc1, const float* __restrict__ fc2,
                             float* __restrict__ sw1, int* __restrict__ idx1,
                             float* __restrict__ sw2, int* __restrict__ idx2) {
  int tid = threadIdx.x;
  if (tid >= 16) return;
  const float* src = (tid < 8) ? fc1 : fc2;
  float* sw = (tid < 8) ? sw1 : sw2;
  int*  idx = (tid < 8) ? idx1 : idx2;
  int e = tid & 7;
  float wv[NP];
  float mx = -1e30f;
  for (int p = 0; p < NP; p++) { wv[p] = src[e * NP + p]; mx = fmaxf(mx, wv[p]); }
  float sum = 0.f;
  for (int p = 0; p < NP; p++) { wv[p] = __expf(wv[p] - mx); sum += wv[p]; }
  float inv = 1.f / sum;
  for (int p = 0; p < NP; p++) wv[p] *= inv;
  float tw[KP]; int ti[KP];
  for (int k = 0; k < KP; k++) {
    int best = 0; float bv = -1.f;
    for (int p = 0; p < NP; p++) if (wv[p] > bv) { bv = wv[p]; best = p; }
    tw[k] = bv; ti[k] = best; wv[best] = -2.f;
  }
  float ts = tw[0] + tw[1] + tw[2] + tw[3];
  float invt = 1.f / (ts + EPSF);
  for (int k = 0; k < KP; k++) {
    sw[e * KP + k] = sqrtf(tw[k] * invt + EPSF);
    idx[e * KP + k] = ti[k];
  }
}

// ---------------- build W1p: fragment-major packed W1 for k1 ---------------
// W1p[((e*2+ntile)*8+k0i)*16 + (wn*2+ks)*4+nt][lane][8] =
//   A1[idx1[e*4+ntile*2+wn]][d = k0i*64+ks*32+(lane>>4)*8+j][r = nt*16+(lane&15)]
//   * sw1[e*4+ntile*2+wn]
__global__ __launch_bounds__(256) void build_W1p(
    const float* __restrict__ A1, const int* __restrict__ idx1,
    const float* __restrict__ sw1, u16* __restrict__ W1p) {
  __shared__ u16 Ta[2 * 64 * 68];
  int bid = blockIdx.x;
  int k0i = bid & 7, ntile = (bid >> 3) & 1, e = bid >> 4;
  int d0 = k0i * 64;
  int tid = threadIdx.x;
  {
    int kk = tid >> 7, row = (tid >> 1) & 63, half = tid & 1;
    int prim = idx1[e * 4 + ntile * 2 + kk];
    float s = sw1[e * 4 + ntile * 2 + kk];
#pragma unroll
    for (int q = 0; q < 8; q++) {
      int r = half * 32 + q * 4;
      float4 v = *(const float4*)(A1 + ((size_t)prim * DM + d0 + row) * RANK + r);
      u16x4v o;
      o[0] = f2bf(v.x * s); o[1] = f2bf(v.y * s);
      o[2] = f2bf(v.z * s); o[3] = f2bf(v.w * s);
      *(u16x4v*)&Ta[(kk * 64 + row) * 68 + r] = o;
    }
  }
  __syncthreads();
  u16* dst = W1p + ((size_t)(e * 2 + ntile) * 8 + k0i) * 8192;
#pragma unroll
  for (int it = 0; it < 4; it++) {
    int slot = it * 256 + tid;
    int lane = slot & 63, rest = slot >> 6;
    int nt = rest & 3, ks = (rest >> 2) & 1, wn = rest >> 3;
    int ln = lane & 15, quad = lane >> 4;
    int r = nt * 16 + ln;
    int db = ks * 32 + quad * 8;
    u16x8v o;
#pragma unroll
    for (int j = 0; j < 8; j++) o[j] = Ta[(wn * 64 + db + j) * 68 + r];
    *(u16x8v*)&dst[((wn * 8 + ks * 4 + nt) * 64 + lane) * 8] = o;
  }
}

// ---------------- build V1p: fragment-major packed V1 for k23 phase A ------
__global__ __launch_bounds__(256) void build_V1p(
    const float* __restrict__ B1, const int* __restrict__ idx1,
    const float* __restrict__ sw1, u16* __restrict__ V1p) {
  __shared__ u16 Tb[64 * 132];
  int bid = blockIdx.x;
  int p = bid & 3, f0i = (bid >> 2) & 15, e = bid >> 6;
  int prim = idx1[e * 4 + p];
  float s = sw1[e * 4 + p];
  int f0 = f0i * 128;
  int tid = threadIdx.x;
  {
    int r = tid >> 2, fq = (tid & 3) * 32;
#pragma unroll
    for (int q = 0; q < 8; q++) {
      int fl = fq + q * 4;
      float4 v = *(const float4*)(B1 + ((size_t)prim * RANK + r) * DFF + f0 + fl);
      u16x4v o;
      o[0] = f2bf(v.x * s); o[1] = f2bf(v.y * s);
      o[2] = f2bf(v.z * s); o[3] = f2bf(v.w * s);
      *(u16x4v*)&Tb[r * 132 + fl] = o;
    }
  }
  __syncthreads();
  u16* dst = V1p + ((size_t)e << 19) + f0i * 32768 + p * 8192;
#pragma unroll
  for (int it = 0; it < 4; it++) {
    int slot = it * 256 + tid;
    int lane = slot & 63, nt = (slot >> 6) & 1, ks = (slot >> 7) & 1, wv = slot >> 8;
    int ln = lane & 15, quad = lane >> 4;
    int fl = wv * 32 + nt * 16 + ln;
    int r0 = ks * 32 + quad * 8;
    u16x8v o;
#pragma unroll
    for (int j = 0; j < 8; j++) o[j] = Tb[(r0 + j) * 132 + fl];
    *(u16x8v*)&dst[(((wv * 2 + ks) * 2 + nt) * 64 + lane) * 8] = o;
  }
}

// ---------------- build W2p: fragment-major packed W2 for k23 phase B ------
__global__ __launch_bounds__(256) void build_W2p(
    const float* __restrict__ A2, const int* __restrict__ idx2,
    const float* __restrict__ sw2, u16* __restrict__ W2p) {
  __shared__ u16 Ta[2 * 64 * 68];
  int bid = blockIdx.x;
  int c2 = bid & 3, f0i = (bid >> 2) & 15, e = bid >> 6;
  int hh = c2 >> 1, fi = c2 & 1;
  int f0 = f0i * 128 + fi * 64;
  int tid = threadIdx.x;
  {
    int kk = tid >> 7, row = (tid >> 1) & 63, half = tid & 1;
    int prim = idx2[e * 4 + hh * 2 + kk];
    float s = sw2[e * 4 + hh * 2 + kk];
#pragma unroll
    for (int q = 0; q < 8; q++) {
      int r = half * 32 + q * 4;
      float4 v = *(const float4*)(A2 + ((size_t)prim * DFF + f0 + row) * RANK + r);
      u16x4v o;
      o[0] = f2bf(v.x * s); o[1] = f2bf(v.y * s);
      o[2] = f2bf(v.z * s); o[3] = f2bf(v.w * s);
      *(u16x4v*)&Ta[(kk * 64 + row) * 68 + r] = o;
    }
  }
  __syncthreads();
  u16* dst = W2p + ((size_t)e << 19) + f0i * 32768 + c2 * 8192;
#pragma unroll
  for (int it = 0; it < 4; it++) {
    int slot = it * 256 + tid;
    int lane = slot & 63, nt = (slot >> 6) & 1, ks = (slot >> 7) & 1, wv = slot >> 8;
    int ln = lane & 15, quad = lane >> 4;
    int kk = wv >> 1;
    int r = (wv & 1) * 32 + nt * 16 + ln;
    int fb = ks * 32 + quad * 8;
    u16x8v o;
#pragma unroll
    for (int j = 0; j < 8; j++) o[j] = Ta[(kk * 64 + fb + j) * 68 + r];
    *(u16x8v*)&dst[(((wv * 2 + ks) * 2 + nt) * 64 + lane) * 8] = o;
  }
}

// ---------------- build V2p: fragment-major packed V2 for k4 ---------------
__global__ __launch_bounds__(256) void build_V2p(
    const float* __restrict__ B2, const int* __restrict__ idx2,
    const float* __restrict__ sw2, u16* __restrict__ V2p) {
  __shared__ u16 Tb[64 * 132];
  int bid = blockIdx.x;
  int k0i = bid & 3, ntile = (bid >> 2) & 3, e = bid >> 4;
  int prim = idx2[e * 4 + k0i];
  float s = sw2[e * 4 + k0i];
  int tid = threadIdx.x;
  {
    int r = tid >> 2, dq = (tid & 3) * 32;
#pragma unroll
    for (int q = 0; q < 8; q++) {
      int dd = dq + q * 4;
      float4 v = *(const float4*)(B2 + ((size_t)prim * RANK + r) * DM + ntile * 128 + dd);
      u16x4v o;
      o[0] = f2bf(v.x * s); o[1] = f2bf(v.y * s);
      o[2] = f2bf(v.z * s); o[3] = f2bf(v.w * s);
      *(u16x4v*)&Tb[r * 132 + dd] = o;
    }
  }
  __syncthreads();
  u16* dst = V2p + ((size_t)(e * 4 + ntile) * 4 + k0i) * 8192;
#pragma unroll
  for (int it = 0; it < 4; it++) {
    int slot = it * 256 + tid;
    int lane = slot & 63, rest = slot >> 6;
    int nt = rest & 3, ks = (rest >> 2) & 1, wn = rest >> 3;
    int ln = lane & 15, quad = lane >> 4;
    int dd = wn * 64 + nt * 16 + ln;
    int r0 = ks * 32 + quad * 8;
    u16x8v o;
#pragma unroll
    for (int j = 0; j < 8; j++) o[j] = Tb[(r0 + j) * 132 + dd];
    *(u16x8v*)&dst[((wn * 8 + ks * 4 + nt) * 64 + lane) * 8] = o;
  }
}

// ---------------- router, token-per-lane (k-split 4) ----------------
__global__ __launch_bounds__(256) void router_kernel(
    const float* __restrict__ x, const float* __restrict__ Wr,
    float* __restrict__ probsum, int* __restrict__ eidx,
    float* __restrict__ gate) {
  __shared__ float wr_s[NE * 4 * 132];
  __shared__ float ps_s[NE];
  int tid = threadIdx.x;
  if (tid < NE) ps_s[tid] = 0.f;
  for (int i = tid; i < NE * DM; i += 256) {
    int e = i >> 9, k = i & 511;
    wr_s[(e * 4 + (k >> 7)) * 132 + (k & 127)] = Wr[i];
  }
  __syncthreads();
  int lane = tid & 63, wv = tid >> 6;
  int tl = lane & 15, sl = lane >> 4;
  int t = blockIdx.x * 64 + wv * 16 + tl;
  const float* xp = x + (size_t)t * DM + sl * 128;
  const float* wp = &wr_s[sl * 132];
  float acc[NE];
#pragma unroll
  for (int e = 0; e < NE; e++) acc[e] = 0.f;
  for (int c = 0; c < 32; c++) {
    float4 xv = *(const float4*)(xp + c * 4);
#pragma unroll
    for (int e = 0; e < NE; e++) {
      float4 w4 = *(const float4*)(wp + e * 4 * 132 + c * 4);
      acc[e] += xv.x * w4.x + xv.y * w4.y + xv.z * w4.z + xv.w * w4.w;
    }
  }
#pragma unroll
  for (int e = 0; e < NE; e++) {
    acc[e] += __shfl_xor(acc[e], 16, 64);
    acc[e] += __shfl_xor(acc[e], 32, 64);
  }
  if (sl == 0) {
    float mx = acc[0];
#pragma unroll
    for (int e = 1; e < NE; e++) mx = fmaxf(mx, acc[e]);
    float pe[NE]; float sum = 0.f;
#pragma unroll
    for (int e = 0; e < NE; e++) { pe[e] = __expf(acc[e] - mx); sum += pe[e]; }
    float inv = 1.f / sum;
#pragma unroll
    for (int e = 0; e < NE; e++) pe[e] *= inv;
    int i0 = 0;
#pragma unroll
    for (int e = 1; e < NE; e++) if (pe[e] > pe[i0]) i0 = e;
    int i1 = (i0 == 0) ? 1 : 0;
#pragma unroll
    for (int e = 0; e < NE; e++) if (e != i0 && pe[e] > pe[i1]) i1 = e;
    float p0 = pe[i0], p1 = pe[i1];
    float gd = 1.f / (p0 + p1 + EPSF);
    eidx[t] = i0 | (i1 << 3);
    gate[i0 * T_TOK + t] = p0 * gd;
    gate[i1 * T_TOK + t] = p1 * gd;
#pragma unroll
    for (int e = 0; e < NE; e++) atomicAdd(&ps_s[e], pe[e]);
  }
  __syncthreads();
  if (tid < NE) atomicAdd(&probsum[tid * 64 + (blockIdx.x & 63)], ps_s[tid]);
}

// ---------------- scatter (block-aggregated cnt) + per-token slot pairs ----------
__global__ void scatter_kernel(const int* __restrict__ eidx,
                               int* __restrict__ cnt, int* __restrict__ perm,
                               int* __restrict__ slots) {
  __shared__ int hist[NE], base[NE];
  int tid = threadIdx.x;
  if (tid < NE) hist[tid] = 0;
  __syncthreads();
  int t = blockIdx.x * 256 + tid;
  int pk = eidx[t];
  int e0 = pk & 7, e1 = (pk >> 3) & 7;
  int p0 = atomicAdd(&hist[e0], 1);
  int p1 = atomicAdd(&hist[e1], 1);
  __syncthreads();
  if (tid < NE) base[tid] = atomicAdd(&cnt[tid], hist[tid]);
  __syncthreads();
  int g0 = base[e0] + p0; if (g0 >= CAP) g0 = CAP - 1;
  int g1 = base[e1] + p1; if (g1 >= CAP) g1 = CAP - 1;
  perm[e0 * T_TOK + g0] = t;
  perm[e1 * T_TOK + g1] = t;
  slots[t * 2]     = e0 * CAP + g0;
  slots[t * 2 + 1] = e1 * CAP + g1;
}

// ---------------- aux loss (one wave) ----------------
__global__ void aux_kernel(const int* __restrict__ cnt, const float* __restrict__ probsum,
                           float* __restrict__ aux_out) {
  int lane = threadIdx.x;
  if (lane >= 64) return;
  float s[NE];
#pragma unroll
  for (int e = 0; e < NE; e++) {
    float v = probsum[e * 64 + lane];
#pragma unroll
    for (int off = 32; off > 0; off >>= 1) v += __shfl_xor(v, off, 64);
    s[e] = v;
  }
  if (lane == 0) {
    float c[NE]; float cs = 0.f;
    for (int e = 0; e < NE; e++) { c[e] = (float)cnt[e]; cs += c[e]; }
    float aux = 0.f;
    for (int e = 0; e < NE; e++)
      aux += (c[e] / (cs + EPSF)) * (s[e] / (float)T_TOK);
    *aux_out = (float)NE * aux;
  }
}

// ================= FFN pipeline =================
// All FFN kernels decode expert = bid & 7 (XCD affinity, R3-confirmed).
// R8/R9: fragment-packed B direct global->register (k23 220->159, k1/k4).

// K1 v2: u[slot,256] = bf16( gather(x) @ A1c ), B from packed W1p.
__global__ __launch_bounds__(256) void k1_u(
    const float* __restrict__ x, const int* __restrict__ cnt,
    const int* __restrict__ perm, const u16* __restrict__ W1p,
    u16* __restrict__ u) {
  __shared__ __align__(16) u16 As[8192];
  __shared__ int tok_s[128];
  int bid = blockIdx.x;
  int e = bid & 7;
  int r0 = bid >> 3;
  int ntile = r0 & 1, mt = r0 >> 1;
  int m0 = mt << 7;
  int cntE = cnt[e];
  if (m0 >= cntE) return;
  int tid = threadIdx.x;
  if (tid < 128) {
    int mm = m0 + tid; if (mm > cntE - 1) mm = cntE - 1;
    tok_s[tid] = perm[e * T_TOK + mm];
  }
  __syncthreads();
  int wv = tid >> 6, lane = tid & 63;
  int wm = wv >> 1, wn = wv & 1, ln = lane & 15, quad = lane >> 4;
  int sw = (ln & 7) << 3;
  const u16* Wbase = W1p + ((size_t)(e * 2 + ntile) * 8) * 8192 + (wn * 8 * 64 + lane) * 8;
  f32x4 acc[4][4];
#pragma unroll
  for (int a = 0; a < 4; a++)
#pragma unroll
    for (int b = 0; b < 4; b++) acc[a][b] = (f32x4){0.f, 0.f, 0.f, 0.f};
  for (int k0i = 0; k0i < 8; k0i++) {
    // B fragments (global, L2-resident) — issue before As stage/barrier
    bf16x8 bf[2][4];
    const u16* Wf = Wbase + (size_t)k0i * 8192;
#pragma unroll
    for (int ks = 0; ks < 2; ks++)
#pragma unroll
      for (int nt = 0; nt < 4; nt++)
        bf[ks][nt] = *(const bf16x8*)&Wf[(ks * 4 + nt) * 512];
    // As stage: gather x rows, cvt, swizzled write
    for (int i = tid; i < 2048; i += 256) {
      int row = i >> 4, c4 = i & 15;
      float4 v = *(const float4*)(x + (size_t)tok_s[row] * DM + k0i * 64 + c4 * 4);
      u16x4v o; o[0] = f2bf(v.x); o[1] = f2bf(v.y); o[2] = f2bf(v.z); o[3] = f2bf(v.w);
      *(u16x4v*)&As[row * 64 + ((c4 * 4) ^ ((row & 7) << 3))] = o;
    }
    __syncthreads();
#pragma unroll
    for (int ks = 0; ks < 2; ks++) {
      bf16x8 af[4];
      int co = (ks * 32 + quad * 8) ^ sw;
#pragma unroll
      for (int mt2 = 0; mt2 < 4; mt2++)
        af[mt2] = *(const bf16x8*)&As[(wm * 64 + mt2 * 16 + ln) * 64 + co];
      __builtin_amdgcn_s_setprio(1);
#pragma unroll
      for (int mt2 = 0; mt2 < 4; mt2++)
#pragma unroll
        for (int nt = 0; nt < 4; nt++)
          acc[mt2][nt] = __builtin_amdgcn_mfma_f32_16x16x32_bf16(af[mt2], bf[ks][nt], acc[mt2][nt], 0, 0, 0);
      __builtin_amdgcn_s_setprio(0);
    }
    __syncthreads();
  }
  int slot0 = e * CAP + m0;
#pragma unroll
  for (int mt2 = 0; mt2 < 4; mt2++)
#pragma unroll
    for (int nt = 0; nt < 4; nt++)
#pragma unroll
      for (int r = 0; r < 4; r++) {
        int row = wm * 64 + mt2 * 16 + quad * 4 + r;
        int col = ntile * 128 + wn * 64 + nt * 16 + ln;
        u[(size_t)(slot0 + row) * KR + col] = f2bf(acc[mt2][nt][r]);
      }
}

// K23 v11: t = gelu(u @ B1c) @ A2c — u-tile REGISTER-resident.
// R10 analysis: phase-A LDS reads were 4x wave-duplicated (all waves read the
// same 64 token rows): 2 MB of LDS reads per block for a 32 KB tile, ~half the
// critical LDS-pipe load. The per-lane phase-A fragment set is exactly 256
// bf16 = 128 VGPRs -> load u ONCE from global into registers, reuse across all
// 16 f0i. Deletes the Us prologue + all phase-A LDS reads + phase-A barriers.
// LDS = Hs 16 KB only. VGPR ~220 at 2 waves/SIMD (launch_bounds(256,2)).
// WATCH: WRITE_SIZE balloon => spill => revert.
__global__ __launch_bounds__(256, 2) void k23(
    const u16* __restrict__ u, const int* __restrict__ cnt,
    const u16* __restrict__ V1p, const u16* __restrict__ W2p,
    u16* __restrict__ t) {
  __shared__ __align__(16) u16 Hs[64 * 128];      // 16 KB gelu tile (swizzled)
  int bid = blockIdx.x;
  int e = bid & 7, mt = bid >> 3;
  int m0 = mt << 6;
  int cntE = cnt[e];
  if (m0 >= cntE) return;
  int tid = threadIdx.x;
  int slot0 = e * CAP + m0;
  const u16* ub = u + (size_t)slot0 * KR;

  int wv = tid >> 6, lane = tid & 63;
  int ln = lane & 15, quad = lane >> 4;
  int sw = (ln & 7) << 3;

  // ---- u tile -> registers: ureg[p][ks][m] = u[m*16+ln][p*64+ks*32+quad*8..]
  // 32 x bf16x8 = 128 VGPRs, loaded once, reused 16x (all f0i).
  bf16x8 ureg[4][2][4];
#pragma unroll
  for (int p = 0; p < 4; p++)
#pragma unroll
    for (int ks = 0; ks < 2; ks++)
#pragma unroll
      for (int m = 0; m < 4; m++)
        ureg[p][ks][m] = *(const bf16x8*)&ub[(size_t)(m * 16 + ln) * KR + p * 64 + ks * 32 + quad * 8];

  // packed weight bases: [e][f0i][p|c2][wv][ks][nt][lane][8]
  const u16* V1w = V1p + ((size_t)e << 19) + wv * 2048 + lane * 8;
  const u16* W2w = W2p + ((size_t)e << 19) + wv * 2048 + lane * 8;

  f32x4 tacc[4][4];   // [m][hh*2+nt] ; wave wv owns t cols hh*128 + wv*32 + nt*16 + ln
#pragma unroll
  for (int a = 0; a < 4; a++)
#pragma unroll
    for (int b = 0; b < 4; b++) tacc[a][b] = (f32x4){0.f, 0.f, 0.f, 0.f};
  f32x4 hacc[4][2];

  for (int f0i = 0; f0i < 16; f0i++) {
    const u16* V1f = V1w + f0i * 32768;
    const u16* W2f = W2w + f0i * 32768;
    // ---- phase A: h(64x128) += u @ V1 (regs + L2, NO LDS, NO barriers) ----
#pragma unroll
    for (int p = 0; p < 4; p++) {
      bf16x8 bf[2][2];
#pragma unroll
      for (int ks = 0; ks < 2; ks++)
#pragma unroll
        for (int nt = 0; nt < 2; nt++)
          bf[ks][nt] = *(const bf16x8*)&V1f[p * 8192 + (ks * 2 + nt) * 512];
      if (p == 0) {
#pragma unroll
        for (int a = 0; a < 4; a++)
#pragma unroll
          for (int b = 0; b < 2; b++) hacc[a][b] = (f32x4){0.f, 0.f, 0.f, 0.f};
      }
      __builtin_amdgcn_s_setprio(1);
#pragma unroll
      for (int ks = 0; ks < 2; ks++)
#pragma unroll
        for (int m = 0; m < 4; m++)
#pragma unroll
          for (int nt = 0; nt < 2; nt++)
            hacc[m][nt] = __builtin_amdgcn_mfma_f32_16x16x32_bf16(ureg[p][ks][m], bf[ks][nt], hacc[m][nt], 0, 0, 0);
      __builtin_amdgcn_s_setprio(0);
    }
    // ---- barrier 1: all waves done reading PREVIOUS f0i's Hs ----
    __syncthreads();
    // gelu -> Hs (swizzled write matches swizzled read)
#pragma unroll
    for (int m = 0; m < 4; m++)
#pragma unroll
      for (int nt = 0; nt < 2; nt++)
#pragma unroll
        for (int r = 0; r < 4; r++) {
          int row = m * 16 + quad * 4 + r;
          int col = wv * 32 + nt * 16 + ln;
          float v = hacc[m][nt][r];
          float s = 1.f / (1.f + __expf(-1.702f * v));
          Hs[(row << 7) + (col ^ ((row & 7) << 3))] = f2bf(v * s);
        }
    // ---- barrier 2: publish Hs ----
    __syncthreads();
    // ---- phase B: tacc += gelu(h) @ W2 (4 chunks, NO barriers) ----
#pragma unroll
    for (int c2 = 0; c2 < 4; c2++) {
      const int hh = c2 >> 1, fi = c2 & 1;
      bf16x8 bf[2][2], af[2][4];
#pragma unroll
      for (int ks = 0; ks < 2; ks++)
#pragma unroll
        for (int nt = 0; nt < 2; nt++)
          bf[ks][nt] = *(const bf16x8*)&W2f[c2 * 8192 + (ks * 2 + nt) * 512];
#pragma unroll
      for (int ks = 0; ks < 2; ks++) {
        int ch = (fi * 64 + ks * 32 + quad * 8) ^ sw;
#pragma unroll
        for (int m = 0; m < 4; m++)
          af[ks][m] = *(const bf16x8*)&Hs[((m * 16 + ln) << 7) + ch];
      }
      __builtin_amdgcn_s_setprio(1);
#pragma unroll
      for (int ks = 0; ks < 2; ks++)
#pragma unroll
        for (int m = 0; m < 4; m++)
#pragma unroll
          for (int nt = 0; nt < 2; nt++)
            tacc[m][hh * 2 + nt] = __builtin_amdgcn_mfma_f32_16x16x32_bf16(af[ks][m], bf[ks][nt], tacc[m][hh * 2 + nt], 0, 0, 0);
      __builtin_amdgcn_s_setprio(0);
    }
  }
  // epilogue: t (bf16, written once — no RMW)
#pragma unroll
  for (int m = 0; m < 4; m++)
#pragma unroll
    for (int hh = 0; hh < 2; hh++)
#pragma unroll
      for (int nt = 0; nt < 2; nt++)
#pragma unroll
        for (int r = 0; r < 4; r++) {
          int row = m * 16 + quad * 4 + r;
          int col = hh * 128 + wv * 32 + nt * 16 + ln;
          t[(size_t)(slot0 + row) * KR + col] = f2bf(tacc[m][hh * 2 + nt][r]);
        }
}

// K4 v2: y[slot, 512] = gate * (t @ B2c), B from packed V2p.
__global__ __launch_bounds__(256) void k4_y(
    const u16* __restrict__ t, const int* __restrict__ cnt,
    const int* __restrict__ perm, const float* __restrict__ gate,
    const u16* __restrict__ V2p, u16* __restrict__ y) {
  __shared__ __align__(16) u16 As[8192];
  __shared__ float g_s[128];
  int bid = blockIdx.x;
  int e = bid & 7;
  int r0 = bid >> 3;
  int ntile = r0 & 3, mt = r0 >> 2;
  int m0 = mt << 7;
  int cntE = cnt[e];
  if (m0 >= cntE) return;
  int tid = threadIdx.x;
  if (tid < 128) {
    int mm = m0 + tid; if (mm > cntE - 1) mm = cntE - 1;
    int tk = perm[e * T_TOK + mm];
    g_s[tid] = gate[e * T_TOK + tk];
  }
  __syncthreads();
  int slot0 = e * CAP + m0;
  const u16* Abase = t + (size_t)slot0 * KR;
  int wv = tid >> 6, lane = tid & 63;
  int wm = wv >> 1, wn = wv & 1, ln = lane & 15, quad = lane >> 4;
  int sw = (ln & 7) << 3;
  const u16* Wbase = V2p + ((size_t)(e * 4 + ntile) * 4) * 8192 + (wn * 8 * 64 + lane) * 8;
  f32x4 acc[4][4];
#pragma unroll
  for (int a = 0; a < 4; a++)
#pragma unroll
    for (int b = 0; b < 4; b++) acc[a][b] = (f32x4){0.f, 0.f, 0.f, 0.f};
  for (int k0i = 0; k0i < 4; k0i++) {
    // B fragments (global, L2) — issue before As stage/barrier
    bf16x8 bf[2][4];
    const u16* Wf = Wbase + (size_t)k0i * 8192;
#pragma unroll
    for (int ks = 0; ks < 2; ks++)
#pragma unroll
      for (int nt = 0; nt < 4; nt++)
        bf[ks][nt] = *(const bf16x8*)&Wf[(ks * 4 + nt) * 512];
    stage_tile(Abase + k0i * 64, KR, As, tid);
    __syncthreads();
#pragma unroll
    for (int ks = 0; ks < 2; ks++) {
      bf16x8 af[4];
      int co = (ks * 32 + quad * 8) ^ sw;
#pragma unroll
      for (int mt2 = 0; mt2 < 4; mt2++)
        af[mt2] = *(const bf16x8*)&As[(wm * 64 + mt2 * 16 + ln) * 64 + co];
      __builtin_amdgcn_s_setprio(1);
#pragma unroll
      for (int mt2 = 0; mt2 < 4; mt2++)
#pragma unroll
        for (int nt = 0; nt < 4; nt++)
          acc[mt2][nt] = __builtin_amdgcn_mfma_f32_16x16x32_bf16(af[mt2], bf[ks][nt], acc[mt2][nt], 0, 0, 0);
      __builtin_amdgcn_s_setprio(0);
    }
    __syncthreads();
  }
#pragma unroll
  for (int mt2 = 0; mt2 < 4; mt2++)
#pragma unroll
    for (int nt = 0; nt < 4; nt++)
#pragma unroll
      for (int r = 0; r < 4; r++) {
        int row = wm * 64 + mt2 * 16 + quad * 4 + r;
        int col = ntile * 128 + wn * 64 + nt * 16 + ln;
        y[(size_t)(slot0 + row) * DM + col] = f2bf(acc[mt2][nt][r] * g_s[row]);
      }
}

// gather: out[t] = y[slotA] + y[slotB]
__global__ void gather_kernel(const u16* __restrict__ y, const int* __restrict__ slots,
                              float* __restrict__ out) {
  int idx = blockIdx.x * 256 + threadIdx.x;
  int t = idx >> 7, c4 = (idx & 127) * 4;
  int sA = slots[t * 2], sB = slots[t * 2 + 1];
  u16x4v a = *(const u16x4v*)&y[(size_t)sA * DM + c4];
  u16x4v b = *(const u16x4v*)&y[(size_t)sB * DM + c4];
  float4 o;
  o.x = bf2f(a[0]) + bf2f(b[0]);
  o.y = bf2f(a[1]) + bf2f(b[1]);
  o.z = bf2f(a[2]) + bf2f(b[2]);
  o.w = bf2f(a[3]) + bf2f(b[3]);
  *(float4*)&out[(size_t)t * DM + c4] = o;
}

// ---------------- launch ----------------
extern "C" void kernel_launch(void* const* d_in, const int* in_sizes, int n_in,
                              void* d_out, int out_size, void* d_ws, size_t ws_size,
                              hipStream_t stream) {
  const float* x   = (const float*)d_in[0];
  const float* Wr  = (const float*)d_in[1];
  const float* fc1 = (const float*)d_in[2];
  const float* fc2 = (const float*)d_in[3];
  const float* A1  = (const float*)d_in[4];
  const float* B1  = (const float*)d_in[5];
  const float* A2  = (const float*)d_in[6];
  const float* B2  = (const float*)d_in[7];
  float* out = (float*)d_out;

  char* ws = (char*)d_ws;
  float* sw1     = (float*)(ws + 0);
  int*   idx1    = (int*)(ws + 512);
  float* sw2     = (float*)(ws + 1024);
  int*   idx2    = (int*)(ws + 1536);
  int*   cnt     = (int*)(ws + 2048);
  float* probsum = (float*)(ws + 2560);
  int*   eidx    = (int*)(ws + 8192);                      // 64 KB
  int*   slots   = (int*)(ws + 8192 + 65536);              // 128 KB
  float* gate    = (float*)(ws + 8192 + 65536 + 131072);   // 512 KB
  int*   perm    = (int*)(ws + 8192 + 65536 + 131072 + 524288); // 512 KB
  u16*   W1p     = (u16*)(ws + 8192 + 65536 + 131072 + 2 * 524288);
  u16*   V1p     = W1p + 1048576;     // packed V1: 8 MB
  u16*   W2p     = V1p + 4194304;     // packed W2: 8 MB
  u16*   V2p     = W2p + 4194304;     // packed V2: 2 MB
  char*  endW    = (char*)(V2p + 1048576);                   // ~22.2 MB
  u16*   u_buf   = (u16*)endW;                               // 49152x256 bf16 = 25.2 MB
  u16*   t_buf   = (u16*)(endW + 25165824);                  // 49152x256 bf16 = 25.2 MB
  u16*   y_buf   = (u16*)(endW + 2 * 25165824);              // 49152x512 bf16 = 50.3 MB
  // total ws use ≈ 123 MB

  zero_kernel<<<3, 256, 0, stream>>>(cnt, probsum);
  compose_meta<<<1, 64, 0, stream>>>(fc1, fc2, sw1, idx1, sw2, idx2);
  build_W1p<<<128, 256, 0, stream>>>(A1, idx1, sw1, W1p);
  build_V1p<<<512, 256, 0, stream>>>(B1, idx1, sw1, V1p);
  build_W2p<<<512, 256, 0, stream>>>(A2, idx2, sw2, W2p);
  build_V2p<<<128, 256, 0, stream>>>(B2, idx2, sw2, V2p);
  router_kernel<<<T_TOK / 64, 256, 0, stream>>>(x, Wr, probsum, eidx, gate);
  scatter_kernel<<<T_TOK / 256, 256, 0, stream>>>(eidx, cnt, perm, slots);
  aux_kernel<<<1, 64, 0, stream>>>(cnt, probsum, out + (out_size - 1));

  k1_u<<<2 * NE * MT_E, 256, 0, stream>>>(x, cnt, perm, W1p, u_buf);
  k23<<<NE * (CAP / 64), 256, 0, stream>>>(u_buf, cnt, V1p, W2p, t_buf);
  k4_y<<<4 * NE * MT_E, 256, 0, stream>>>(t_buf, cnt, perm, gate, V2p, y_buf);
  gather_kernel<<<T_TOK * DM / 4 / 256, 256, 0, stream>>>(y_buf, slots, out);
}

// Round 12
// 362.195 us; speedup vs baseline: 1.2438x; 1.2438x over previous
//
#include <hip/hip_runtime.h>

// ---------------- problem constants ----------------
#define T_TOK 16384
#define DM    512
#define DFF   2048
#define NE    8
#define NP    16
#define KP    4
#define RANK  64
#define KR    256           // KP * RANK
#define EPSF  1e-8f
#define CAP   6144          // per-expert pair capacity (expected ~4096)
#define MT_E  48            // CAP / 128 M-tiles per expert

typedef unsigned short u16;
typedef __bf16 bf16x8 __attribute__((ext_vector_type(8)));
typedef float  f32x4  __attribute__((ext_vector_type(4)));
typedef unsigned short u16x8v __attribute__((ext_vector_type(8)));
typedef unsigned short u16x4v __attribute__((ext_vector_type(4)));

typedef __attribute__((address_space(3))) void as3_void;
typedef __attribute__((address_space(1))) void as1_void;

__device__ __forceinline__ u16 f2bf(float f) {
  return __builtin_bit_cast(u16, (__bf16)f);    // native RTNE cvt (R7)
}
__device__ __forceinline__ float bf2f(u16 v) {
  unsigned int u = ((unsigned int)v) << 16;
  return __builtin_bit_cast(float, u);
}

__device__ __forceinline__ void gl_lds16(const u16* g, u16* l) {
  __builtin_amdgcn_global_load_lds((as1_void*)g, (as3_void*)l, 16, 0, 0);
}

// ---- 3-bit XOR swizzle for 64-col (128 B row-stride) LDS tiles ----
// granule' = granule ^ (row&7); readers XOR col with ((row&7)<<3) == per-lane
// (ln&7)<<3. (R6: st_16x32 1-bit variant is WRONG for this layout.)

// stage 128x64 bf16 tile into LDS, source pre-swizzled (gl_lds dst linear)
__device__ __forceinline__ void stage_tile(const u16* g, int ld, u16* lds_tile, int tid) {
  int row = tid >> 3, cc = tid & 7;
#pragma unroll
  for (int ri = 0; ri < 4; ri++) {
    int rg = ri * 32 + row;
    gl_lds16(g + (size_t)rg * ld + ((cc ^ (rg & 7)) * 8), &lds_tile[rg * 64 + cc * 8]);
  }
}

// ---------------- zero counters ----------------
__global__ void zero_kernel(int* __restrict__ cnt, float* __restrict__ probsum) {
  int i = blockIdx.x * 256 + threadIdx.x;
  if (i < NE) cnt[i] = 0;
  if (i >= NE && i < NE + NE * 64) probsum[i - NE] = 0.f;
}

// ---------------- primitive-bank softmax + top-4 ----------------
__global__ void compose_meta(const float* __restrict__ fc1, const float* __restrict__ fc2,
                             float* __restrict__ sw1, int* __restrict__ idx1,
                             float* __restrict__ sw2, int* __restrict__ idx2) {
  int tid = threadIdx.x;
  if (tid >= 16) return;
  const float* src = (tid < 8) ? fc1 : fc2;
  float* sw = (tid < 8) ? sw1 : sw2;
  int*  idx = (tid < 8) ? idx1 : idx2;
  int e = tid & 7;
  float wv[NP];
  float mx = -1e30f;
  for (int p = 0; p < NP; p++) { wv[p] = src[e * NP + p]; mx = fmaxf(mx, wv[p]); }
  float sum = 0.f;
  for (int p = 0; p < NP; p++) { wv[p] = __expf(wv[p] - mx); sum += wv[p]; }
  float inv = 1.f / sum;
  for (int p = 0; p < NP; p++) wv[p] *= inv;
  float tw[KP]; int ti[KP];
  for (int k = 0; k < KP; k++) {
    int best = 0; float bv = -1.f;
    for (int p = 0; p < NP; p++) if (wv[p] > bv) { bv = wv[p]; best = p; }
    tw[k] = bv; ti[k] = best; wv[best] = -2.f;
  }
  float ts = tw[0] + tw[1] + tw[2] + tw[3];
  float invt = 1.f / (ts + EPSF);
  for (int k = 0; k < KP; k++) {
    sw[e * KP + k] = sqrtf(tw[k] * invt + EPSF);
    idx[e * KP + k] = ti[k];
  }
}

// ---------------- build W1p: fragment-major packed W1 for k1 ---------------
__global__ __launch_bounds__(256) void build_W1p(
    const float* __restrict__ A1, const int* __restrict__ idx1,
    const float* __restrict__ sw1, u16* __restrict__ W1p) {
  __shared__ u16 Ta[2 * 64 * 68];
  int bid = blockIdx.x;
  int k0i = bid & 7, ntile = (bid >> 3) & 1, e = bid >> 4;
  int d0 = k0i * 64;
  int tid = threadIdx.x;
  {
    int kk = tid >> 7, row = (tid >> 1) & 63, half = tid & 1;
    int prim = idx1[e * 4 + ntile * 2 + kk];
    float s = sw1[e * 4 + ntile * 2 + kk];
#pragma unroll
    for (int q = 0; q < 8; q++) {
      int r = half * 32 + q * 4;
      float4 v = *(const float4*)(A1 + ((size_t)prim * DM + d0 + row) * RANK + r);
      u16x4v o;
      o[0] = f2bf(v.x * s); o[1] = f2bf(v.y * s);
      o[2] = f2bf(v.z * s); o[3] = f2bf(v.w * s);
      *(u16x4v*)&Ta[(kk * 64 + row) * 68 + r] = o;
    }
  }
  __syncthreads();
  u16* dst = W1p + ((size_t)(e * 2 + ntile) * 8 + k0i) * 8192;
#pragma unroll
  for (int it = 0; it < 4; it++) {
    int slot = it * 256 + tid;
    int lane = slot & 63, rest = slot >> 6;
    int nt = rest & 3, ks = (rest >> 2) & 1, wn = rest >> 3;
    int ln = lane & 15, quad = lane >> 4;
    int r = nt * 16 + ln;
    int db = ks * 32 + quad * 8;
    u16x8v o;
#pragma unroll
    for (int j = 0; j < 8; j++) o[j] = Ta[(wn * 64 + db + j) * 68 + r];
    *(u16x8v*)&dst[((wn * 8 + ks * 4 + nt) * 64 + lane) * 8] = o;
  }
}

// ---------------- build V1p: fragment-major packed V1 for k23 phase A ------
__global__ __launch_bounds__(256) void build_V1p(
    const float* __restrict__ B1, const int* __restrict__ idx1,
    const float* __restrict__ sw1, u16* __restrict__ V1p) {
  __shared__ u16 Tb[64 * 132];
  int bid = blockIdx.x;
  int p = bid & 3, f0i = (bid >> 2) & 15, e = bid >> 6;
  int prim = idx1[e * 4 + p];
  float s = sw1[e * 4 + p];
  int f0 = f0i * 128;
  int tid = threadIdx.x;
  {
    int r = tid >> 2, fq = (tid & 3) * 32;
#pragma unroll
    for (int q = 0; q < 8; q++) {
      int fl = fq + q * 4;
      float4 v = *(const float4*)(B1 + ((size_t)prim * RANK + r) * DFF + f0 + fl);
      u16x4v o;
      o[0] = f2bf(v.x * s); o[1] = f2bf(v.y * s);
      o[2] = f2bf(v.z * s); o[3] = f2bf(v.w * s);
      *(u16x4v*)&Tb[r * 132 + fl] = o;
    }
  }
  __syncthreads();
  u16* dst = V1p + ((size_t)e << 19) + f0i * 32768 + p * 8192;
#pragma unroll
  for (int it = 0; it < 4; it++) {
    int slot = it * 256 + tid;
    int lane = slot & 63, nt = (slot >> 6) & 1, ks = (slot >> 7) & 1, wv = slot >> 8;
    int ln = lane & 15, quad = lane >> 4;
    int fl = wv * 32 + nt * 16 + ln;
    int r0 = ks * 32 + quad * 8;
    u16x8v o;
#pragma unroll
    for (int j = 0; j < 8; j++) o[j] = Tb[(r0 + j) * 132 + fl];
    *(u16x8v*)&dst[(((wv * 2 + ks) * 2 + nt) * 64 + lane) * 8] = o;
  }
}

// ---------------- build W2p: fragment-major packed W2 for k23 phase B ------
__global__ __launch_bounds__(256) void build_W2p(
    const float* __restrict__ A2, const int* __restrict__ idx2,
    const float* __restrict__ sw2, u16* __restrict__ W2p) {
  __shared__ u16 Ta[2 * 64 * 68];
  int bid = blockIdx.x;
  int c2 = bid & 3, f0i = (bid >> 2) & 15, e = bid >> 6;
  int hh = c2 >> 1, fi = c2 & 1;
  int f0 = f0i * 128 + fi * 64;
  int tid = threadIdx.x;
  {
    int kk = tid >> 7, row = (tid >> 1) & 63, half = tid & 1;
    int prim = idx2[e * 4 + hh * 2 + kk];
    float s = sw2[e * 4 + hh * 2 + kk];
#pragma unroll
    for (int q = 0; q < 8; q++) {
      int r = half * 32 + q * 4;
      float4 v = *(const float4*)(A2 + ((size_t)prim * DFF + f0 + row) * RANK + r);
      u16x4v o;
      o[0] = f2bf(v.x * s); o[1] = f2bf(v.y * s);
      o[2] = f2bf(v.z * s); o[3] = f2bf(v.w * s);
      *(u16x4v*)&Ta[(kk * 64 + row) * 68 + r] = o;
    }
  }
  __syncthreads();
  u16* dst = W2p + ((size_t)e << 19) + f0i * 32768 + c2 * 8192;
#pragma unroll
  for (int it = 0; it < 4; it++) {
    int slot = it * 256 + tid;
    int lane = slot & 63, nt = (slot >> 6) & 1, ks = (slot >> 7) & 1, wv = slot >> 8;
    int ln = lane & 15, quad = lane >> 4;
    int kk = wv >> 1;
    int r = (wv & 1) * 32 + nt * 16 + ln;
    int fb = ks * 32 + quad * 8;
    u16x8v o;
#pragma unroll
    for (int j = 0; j < 8; j++) o[j] = Ta[(kk * 64 + fb + j) * 68 + r];
    *(u16x8v*)&dst[(((wv * 2 + ks) * 2 + nt) * 64 + lane) * 8] = o;
  }
}

// ---------------- build V2p: fragment-major packed V2 for k4 ---------------
__global__ __launch_bounds__(256) void build_V2p(
    const float* __restrict__ B2, const int* __restrict__ idx2,
    const float* __restrict__ sw2, u16* __restrict__ V2p) {
  __shared__ u16 Tb[64 * 132];
  int bid = blockIdx.x;
  int k0i = bid & 3, ntile = (bid >> 2) & 3, e = bid >> 4;
  int prim = idx2[e * 4 + k0i];
  float s = sw2[e * 4 + k0i];
  int tid = threadIdx.x;
  {
    int r = tid >> 2, dq = (tid & 3) * 32;
#pragma unroll
    for (int q = 0; q < 8; q++) {
      int dd = dq + q * 4;
      float4 v = *(const float4*)(B2 + ((size_t)prim * RANK + r) * DM + ntile * 128 + dd);
      u16x4v o;
      o[0] = f2bf(v.x * s); o[1] = f2bf(v.y * s);
      o[2] = f2bf(v.z * s); o[3] = f2bf(v.w * s);
      *(u16x4v*)&Tb[r * 132 + dd] = o;
    }
  }
  __syncthreads();
  u16* dst = V2p + ((size_t)(e * 4 + ntile) * 4 + k0i) * 8192;
#pragma unroll
  for (int it = 0; it < 4; it++) {
    int slot = it * 256 + tid;
    int lane = slot & 63, rest = slot >> 6;
    int nt = rest & 3, ks = (rest >> 2) & 1, wn = rest >> 3;
    int ln = lane & 15, quad = lane >> 4;
    int dd = wn * 64 + nt * 16 + ln;
    int r0 = ks * 32 + quad * 8;
    u16x8v o;
#pragma unroll
    for (int j = 0; j < 8; j++) o[j] = Tb[(r0 + j) * 132 + dd];
    *(u16x8v*)&dst[((wn * 8 + ks * 4 + nt) * 64 + lane) * 8] = o;
  }
}

// ---------------- router, token-per-lane (k-split 4) ----------------
__global__ __launch_bounds__(256) void router_kernel(
    const float* __restrict__ x, const float* __restrict__ Wr,
    float* __restrict__ probsum, int* __restrict__ eidx,
    float* __restrict__ gate) {
  __shared__ float wr_s[NE * 4 * 132];
  __shared__ float ps_s[NE];
  int tid = threadIdx.x;
  if (tid < NE) ps_s[tid] = 0.f;
  for (int i = tid; i < NE * DM; i += 256) {
    int e = i >> 9, k = i & 511;
    wr_s[(e * 4 + (k >> 7)) * 132 + (k & 127)] = Wr[i];
  }
  __syncthreads();
  int lane = tid & 63, wv = tid >> 6;
  int tl = lane & 15, sl = lane >> 4;
  int t = blockIdx.x * 64 + wv * 16 + tl;
  const float* xp = x + (size_t)t * DM + sl * 128;
  const float* wp = &wr_s[sl * 132];
  float acc[NE];
#pragma unroll
  for (int e = 0; e < NE; e++) acc[e] = 0.f;
  for (int c = 0; c < 32; c++) {
    float4 xv = *(const float4*)(xp + c * 4);
#pragma unroll
    for (int e = 0; e < NE; e++) {
      float4 w4 = *(const float4*)(wp + e * 4 * 132 + c * 4);
      acc[e] += xv.x * w4.x + xv.y * w4.y + xv.z * w4.z + xv.w * w4.w;
    }
  }
#pragma unroll
  for (int e = 0; e < NE; e++) {
    acc[e] += __shfl_xor(acc[e], 16, 64);
    acc[e] += __shfl_xor(acc[e], 32, 64);
  }
  if (sl == 0) {
    float mx = acc[0];
#pragma unroll
    for (int e = 1; e < NE; e++) mx = fmaxf(mx, acc[e]);
    float pe[NE]; float sum = 0.f;
#pragma unroll
    for (int e = 0; e < NE; e++) { pe[e] = __expf(acc[e] - mx); sum += pe[e]; }
    float inv = 1.f / sum;
#pragma unroll
    for (int e = 0; e < NE; e++) pe[e] *= inv;
    int i0 = 0;
#pragma unroll
    for (int e = 1; e < NE; e++) if (pe[e] > pe[i0]) i0 = e;
    int i1 = (i0 == 0) ? 1 : 0;
#pragma unroll
    for (int e = 0; e < NE; e++) if (e != i0 && pe[e] > pe[i1]) i1 = e;
    float p0 = pe[i0], p1 = pe[i1];
    float gd = 1.f / (p0 + p1 + EPSF);
    eidx[t] = i0 | (i1 << 3);
    gate[i0 * T_TOK + t] = p0 * gd;
    gate[i1 * T_TOK + t] = p1 * gd;
#pragma unroll
    for (int e = 0; e < NE; e++) atomicAdd(&ps_s[e], pe[e]);
  }
  __syncthreads();
  if (tid < NE) atomicAdd(&probsum[tid * 64 + (blockIdx.x & 63)], ps_s[tid]);
}

// ---------------- scatter (block-aggregated cnt) + per-token slot pairs ----------
__global__ void scatter_kernel(const int* __restrict__ eidx,
                               int* __restrict__ cnt, int* __restrict__ perm,
                               int* __restrict__ slots) {
  __shared__ int hist[NE], base[NE];
  int tid = threadIdx.x;
  if (tid < NE) hist[tid] = 0;
  __syncthreads();
  int t = blockIdx.x * 256 + tid;
  int pk = eidx[t];
  int e0 = pk & 7, e1 = (pk >> 3) & 7;
  int p0 = atomicAdd(&hist[e0], 1);
  int p1 = atomicAdd(&hist[e1], 1);
  __syncthreads();
  if (tid < NE) base[tid] = atomicAdd(&cnt[tid], hist[tid]);
  __syncthreads();
  int g0 = base[e0] + p0; if (g0 >= CAP) g0 = CAP - 1;
  int g1 = base[e1] + p1; if (g1 >= CAP) g1 = CAP - 1;
  perm[e0 * T_TOK + g0] = t;
  perm[e1 * T_TOK + g1] = t;
  slots[t * 2]     = e0 * CAP + g0;
  slots[t * 2 + 1] = e1 * CAP + g1;
}

// ---------------- aux loss (one wave) ----------------
__global__ void aux_kernel(const int* __restrict__ cnt, const float* __restrict__ probsum,
                           float* __restrict__ aux_out) {
  int lane = threadIdx.x;
  if (lane >= 64) return;
  float s[NE];
#pragma unroll
  for (int e = 0; e < NE; e++) {
    float v = probsum[e * 64 + lane];
#pragma unroll
    for (int off = 32; off > 0; off >>= 1) v += __shfl_xor(v, off, 64);
    s[e] = v;
  }
  if (lane == 0) {
    float c[NE]; float cs = 0.f;
    for (int e = 0; e < NE; e++) { c[e] = (float)cnt[e]; cs += c[e]; }
    float aux = 0.f;
    for (int e = 0; e < NE; e++)
      aux += (c[e] / (cs + EPSF)) * (s[e] / (float)T_TOK);
    *aux_out = (float)NE * aux;
  }
}

// ================= FFN pipeline =================
// All FFN kernels decode expert = bid & 7 (XCD affinity, R3-confirmed).
// R8/R9: fragment-packed B direct global->register (k23 220->159, k1/k4).

// K1 v2: u[slot,256] = bf16( gather(x) @ A1c ), B from packed W1p.
__global__ __launch_bounds__(256) void k1_u(
    const float* __restrict__ x, const int* __restrict__ cnt,
    const int* __restrict__ perm, const u16* __restrict__ W1p,
    u16* __restrict__ u) {
  __shared__ __align__(16) u16 As[8192];
  __shared__ int tok_s[128];
  int bid = blockIdx.x;
  int e = bid & 7;
  int r0 = bid >> 3;
  int ntile = r0 & 1, mt = r0 >> 1;
  int m0 = mt << 7;
  int cntE = cnt[e];
  if (m0 >= cntE) return;
  int tid = threadIdx.x;
  if (tid < 128) {
    int mm = m0 + tid; if (mm > cntE - 1) mm = cntE - 1;
    tok_s[tid] = perm[e * T_TOK + mm];
  }
  __syncthreads();
  int wv = tid >> 6, lane = tid & 63;
  int wm = wv >> 1, wn = wv & 1, ln = lane & 15, quad = lane >> 4;
  int sw = (ln & 7) << 3;
  const u16* Wbase = W1p + ((size_t)(e * 2 + ntile) * 8) * 8192 + (wn * 8 * 64 + lane) * 8;
  f32x4 acc[4][4];
#pragma unroll
  for (int a = 0; a < 4; a++)
#pragma unroll
    for (int b = 0; b < 4; b++) acc[a][b] = (f32x4){0.f, 0.f, 0.f, 0.f};
  for (int k0i = 0; k0i < 8; k0i++) {
    // B fragments (global, L2-resident) — issue before As stage/barrier
    bf16x8 bf[2][4];
    const u16* Wf = Wbase + (size_t)k0i * 8192;
#pragma unroll
    for (int ks = 0; ks < 2; ks++)
#pragma unroll
      for (int nt = 0; nt < 4; nt++)
        bf[ks][nt] = *(const bf16x8*)&Wf[(ks * 4 + nt) * 512];
    // As stage: gather x rows, cvt, swizzled write
    for (int i = tid; i < 2048; i += 256) {
      int row = i >> 4, c4 = i & 15;
      float4 v = *(const float4*)(x + (size_t)tok_s[row] * DM + k0i * 64 + c4 * 4);
      u16x4v o; o[0] = f2bf(v.x); o[1] = f2bf(v.y); o[2] = f2bf(v.z); o[3] = f2bf(v.w);
      *(u16x4v*)&As[row * 64 + ((c4 * 4) ^ ((row & 7) << 3))] = o;
    }
    __syncthreads();
#pragma unroll
    for (int ks = 0; ks < 2; ks++) {
      bf16x8 af[4];
      int co = (ks * 32 + quad * 8) ^ sw;
#pragma unroll
      for (int mt2 = 0; mt2 < 4; mt2++)
        af[mt2] = *(const bf16x8*)&As[(wm * 64 + mt2 * 16 + ln) * 64 + co];
      __builtin_amdgcn_s_setprio(1);
#pragma unroll
      for (int mt2 = 0; mt2 < 4; mt2++)
#pragma unroll
        for (int nt = 0; nt < 4; nt++)
          acc[mt2][nt] = __builtin_amdgcn_mfma_f32_16x16x32_bf16(af[mt2], bf[ks][nt], acc[mt2][nt], 0, 0, 0);
      __builtin_amdgcn_s_setprio(0);
    }
    __syncthreads();
  }
  int slot0 = e * CAP + m0;
#pragma unroll
  for (int mt2 = 0; mt2 < 4; mt2++)
#pragma unroll
    for (int nt = 0; nt < 4; nt++)
#pragma unroll
      for (int r = 0; r < 4; r++) {
        int row = wm * 64 + mt2 * 16 + quad * 4 + r;
        int col = ntile * 128 + wn * 64 + nt * 16 + ln;
        u[(size_t)(slot0 + row) * KR + col] = f2bf(acc[mt2][nt][r]);
      }
}

// K23 v12: t = gelu(u @ B1c) @ A2c — HALF-register u-tile.
// R11's full 128-VGPR ureg overflowed the 256-VGPR cap of (256,2) ->
// pathological spill (VGPR 128, WRITE 44 MB, 260 us). v12 sizes it to fit:
// p in {0,1} in registers (64 VGPR), p in {2,3} in a 16 KB LDS half-tile.
// Budget: tacc 64 + hacc 32 + ureg 64 + temps/addr ~60 = ~220 < 256.
// Phase-A LDS reads halve vs R10; LDS = Us16 16K + Hs 16K = 32 KB.
// GO/NO-GO: WRITE_SIZE > 25 MB => spill => revert to R10.
__global__ __launch_bounds__(256, 2) void k23(
    const u16* __restrict__ u, const int* __restrict__ cnt,
    const u16* __restrict__ V1p, const u16* __restrict__ W2p,
    u16* __restrict__ t) {
  __shared__ __align__(16) u16 Us16[64 * 128];    // 16 KB: u cols 128..255 (swizzled)
  __shared__ __align__(16) u16 Hs[64 * 128];      // 16 KB gelu tile (swizzled)
  int bid = blockIdx.x;
  int e = bid & 7, mt = bid >> 3;
  int m0 = mt << 6;
  int cntE = cnt[e];
  if (m0 >= cntE) return;
  int tid = threadIdx.x;
  int slot0 = e * CAP + m0;
  const u16* ub = u + (size_t)slot0 * KR;

  // ---- prologue: stage u cols 128..255 into Us16 (src pre-swizzled) ----
#pragma unroll
  for (int r = 0; r < 4; r++) {
    int i = r * 256 + tid;                 // 16 B chunk id, 0..1023
    int row = i >> 4, cc = i & 15;
    gl_lds16(ub + (size_t)row * 256 + 128 + ((cc ^ (row & 7)) * 8), &Us16[i * 8]);
  }

  int wv = tid >> 6, lane = tid & 63;
  int ln = lane & 15, quad = lane >> 4;
  int sw = (ln & 7) << 3;

  // ---- u cols 0..127 -> registers: ureg[p][ks][m], p in {0,1} (64 VGPR) ----
  bf16x8 ureg[2][2][4];
#pragma unroll
  for (int p = 0; p < 2; p++)
#pragma unroll
    for (int ks = 0; ks < 2; ks++)
#pragma unroll
      for (int m = 0; m < 4; m++)
        ureg[p][ks][m] = *(const bf16x8*)&ub[(size_t)(m * 16 + ln) * KR + p * 64 + ks * 32 + quad * 8];

  __syncthreads();                          // drains gl_lds; Us16 ready

  // packed weight bases: [e][f0i][p|c2][wv][ks][nt][lane][8]
  const u16* V1w = V1p + ((size_t)e << 19) + wv * 2048 + lane * 8;
  const u16* W2w = W2p + ((size_t)e << 19) + wv * 2048 + lane * 8;

  f32x4 tacc[4][4];   // [m][hh*2+nt] ; wave wv owns t cols hh*128 + wv*32 + nt*16 + ln
#pragma unroll
  for (int a = 0; a < 4; a++)
#pragma unroll
    for (int b = 0; b < 4; b++) tacc[a][b] = (f32x4){0.f, 0.f, 0.f, 0.f};
  f32x4 hacc[4][2];

  for (int f0i = 0; f0i < 16; f0i++) {
    const u16* V1f = V1w + f0i * 32768;
    const u16* W2f = W2w + f0i * 32768;
    // ---- phase A: h(64x128) += u @ V1 (p 0-1 from regs, p 2-3 from Us16) ----
#pragma unroll
    for (int p = 0; p < 4; p++) {
      bf16x8 bf[2][2];
#pragma unroll
      for (int ks = 0; ks < 2; ks++)
#pragma unroll
        for (int nt = 0; nt < 2; nt++)
          bf[ks][nt] = *(const bf16x8*)&V1f[p * 8192 + (ks * 2 + nt) * 512];
      if (p == 0) {
#pragma unroll
        for (int a = 0; a < 4; a++)
#pragma unroll
          for (int b = 0; b < 2; b++) hacc[a][b] = (f32x4){0.f, 0.f, 0.f, 0.f};
      }
      if (p < 2) {
        __builtin_amdgcn_s_setprio(1);
#pragma unroll
        for (int ks = 0; ks < 2; ks++)
#pragma unroll
          for (int m = 0; m < 4; m++)
#pragma unroll
            for (int nt = 0; nt < 2; nt++)
              hacc[m][nt] = __builtin_amdgcn_mfma_f32_16x16x32_bf16(ureg[p][ks][m], bf[ks][nt], hacc[m][nt], 0, 0, 0);
        __builtin_amdgcn_s_setprio(0);
      } else {
        bf16x8 af[2][4];
#pragma unroll
        for (int ks = 0; ks < 2; ks++) {
          int cu = ((p - 2) * 64 + ks * 32 + quad * 8) ^ sw;
#pragma unroll
          for (int m = 0; m < 4; m++)
            af[ks][m] = *(const bf16x8*)&Us16[((m * 16 + ln) << 7) + cu];
        }
        __builtin_amdgcn_s_setprio(1);
#pragma unroll
        for (int ks = 0; ks < 2; ks++)
#pragma unroll
          for (int m = 0; m < 4; m++)
#pragma unroll
            for (int nt = 0; nt < 2; nt++)
              hacc[m][nt] = __builtin_amdgcn_mfma_f32_16x16x32_bf16(af[ks][m], bf[ks][nt], hacc[m][nt], 0, 0, 0);
        __builtin_amdgcn_s_setprio(0);
      }
    }
    // ---- barrier 1: all waves done reading PREVIOUS f0i's Hs ----
    __syncthreads();
    // gelu -> Hs (swizzled write matches swizzled read)
#pragma unroll
    for (int m = 0; m < 4; m++)
#pragma unroll
      for (int nt = 0; nt < 2; nt++)
#pragma unroll
        for (int r = 0; r < 4; r++) {
          int row = m * 16 + quad * 4 + r;
          int col = wv * 32 + nt * 16 + ln;
          float v = hacc[m][nt][r];
          float s = 1.f / (1.f + __expf(-1.702f * v));
          Hs[(row << 7) + (col ^ ((row & 7) << 3))] = f2bf(v * s);
        }
    // ---- barrier 2: publish Hs ----
    __syncthreads();
    // ---- phase B: tacc += gelu(h) @ W2 (4 chunks, NO barriers) ----
#pragma unroll
    for (int c2 = 0; c2 < 4; c2++) {
      const int hh = c2 >> 1, fi = c2 & 1;
      bf16x8 bf[2][2], af[2][4];
#pragma unroll
      for (int ks = 0; ks < 2; ks++)
#pragma unroll
        for (int nt = 0; nt < 2; nt++)
          bf[ks][nt] = *(const bf16x8*)&W2f[c2 * 8192 + (ks * 2 + nt) * 512];
#pragma unroll
      for (int ks = 0; ks < 2; ks++) {
        int ch = (fi * 64 + ks * 32 + quad * 8) ^ sw;
#pragma unroll
        for (int m = 0; m < 4; m++)
          af[ks][m] = *(const bf16x8*)&Hs[((m * 16 + ln) << 7) + ch];
      }
      __builtin_amdgcn_s_setprio(1);
#pragma unroll
      for (int ks = 0; ks < 2; ks++)
#pragma unroll
        for (int m = 0; m < 4; m++)
#pragma unroll
          for (int nt = 0; nt < 2; nt++)
            tacc[m][hh * 2 + nt] = __builtin_amdgcn_mfma_f32_16x16x32_bf16(af[ks][m], bf[ks][nt], tacc[m][hh * 2 + nt], 0, 0, 0);
      __builtin_amdgcn_s_setprio(0);
    }
  }
  // epilogue: t (bf16, written once — no RMW)
#pragma unroll
  for (int m = 0; m < 4; m++)
#pragma unroll
    for (int hh = 0; hh < 2; hh++)
#pragma unroll
      for (int nt = 0; nt < 2; nt++)
#pragma unroll
        for (int r = 0; r < 4; r++) {
          int row = m * 16 + quad * 4 + r;
          int col = hh * 128 + wv * 32 + nt * 16 + ln;
          t[(size_t)(slot0 + row) * KR + col] = f2bf(tacc[m][hh * 2 + nt][r]);
        }
}

// K4 v2: y[slot, 512] = gate * (t @ B2c), B from packed V2p.
__global__ __launch_bounds__(256) void k4_y(
    const u16* __restrict__ t, const int* __restrict__ cnt,
    const int* __restrict__ perm, const float* __restrict__ gate,
    const u16* __restrict__ V2p, u16* __restrict__ y) {
  __shared__ __align__(16) u16 As[8192];
  __shared__ float g_s[128];
  int bid = blockIdx.x;
  int e = bid & 7;
  int r0 = bid >> 3;
  int ntile = r0 & 3, mt = r0 >> 2;
  int m0 = mt << 7;
  int cntE = cnt[e];
  if (m0 >= cntE) return;
  int tid = threadIdx.x;
  if (tid < 128) {
    int mm = m0 + tid; if (mm > cntE - 1) mm = cntE - 1;
    int tk = perm[e * T_TOK + mm];
    g_s[tid] = gate[e * T_TOK + tk];
  }
  __syncthreads();
  int slot0 = e * CAP + m0;
  const u16* Abase = t + (size_t)slot0 * KR;
  int wv = tid >> 6, lane = tid & 63;
  int wm = wv >> 1, wn = wv & 1, ln = lane & 15, quad = lane >> 4;
  int sw = (ln & 7) << 3;
  const u16* Wbase = V2p + ((size_t)(e * 4 + ntile) * 4) * 8192 + (wn * 8 * 64 + lane) * 8;
  f32x4 acc[4][4];
#pragma unroll
  for (int a = 0; a < 4; a++)
#pragma unroll
    for (int b = 0; b < 4; b++) acc[a][b] = (f32x4){0.f, 0.f, 0.f, 0.f};
  for (int k0i = 0; k0i < 4; k0i++) {
    // B fragments (global, L2) — issue before As stage/barrier
    bf16x8 bf[2][4];
    const u16* Wf = Wbase + (size_t)k0i * 8192;
#pragma unroll
    for (int ks = 0; ks < 2; ks++)
#pragma unroll
      for (int nt = 0; nt < 4; nt++)
        bf[ks][nt] = *(const bf16x8*)&Wf[(ks * 4 + nt) * 512];
    stage_tile(Abase + k0i * 64, KR, As, tid);
    __syncthreads();
#pragma unroll
    for (int ks = 0; ks < 2; ks++) {
      bf16x8 af[4];
      int co = (ks * 32 + quad * 8) ^ sw;
#pragma unroll
      for (int mt2 = 0; mt2 < 4; mt2++)
        af[mt2] = *(const bf16x8*)&As[(wm * 64 + mt2 * 16 + ln) * 64 + co];
      __builtin_amdgcn_s_setprio(1);
#pragma unroll
      for (int mt2 = 0; mt2 < 4; mt2++)
#pragma unroll
        for (int nt = 0; nt < 4; nt++)
          acc[mt2][nt] = __builtin_amdgcn_mfma_f32_16x16x32_bf16(af[mt2], bf[ks][nt], acc[mt2][nt], 0, 0, 0);
      __builtin_amdgcn_s_setprio(0);
    }
    __syncthreads();
  }
#pragma unroll
  for (int mt2 = 0; mt2 < 4; mt2++)
#pragma unroll
    for (int nt = 0; nt < 4; nt++)
#pragma unroll
      for (int r = 0; r < 4; r++) {
        int row = wm * 64 + mt2 * 16 + quad * 4 + r;
        int col = ntile * 128 + wn * 64 + nt * 16 + ln;
        y[(size_t)(slot0 + row) * DM + col] = f2bf(acc[mt2][nt][r] * g_s[row]);
      }
}

// gather: out[t] = y[slotA] + y[slotB]
__global__ void gather_kernel(const u16* __restrict__ y, const int* __restrict__ slots,
                              float* __restrict__ out) {
  int idx = blockIdx.x * 256 + threadIdx.x;
  int t = idx >> 7, c4 = (idx & 127) * 4;
  int sA = slots[t * 2], sB = slots[t * 2 + 1];
  u16x4v a = *(const u16x4v*)&y[(size_t)sA * DM + c4];
  u16x4v b = *(const u16x4v*)&y[(size_t)sB * DM + c4];
  float4 o;
  o.x = bf2f(a[0]) + bf2f(b[0]);
  o.y = bf2f(a[1]) + bf2f(b[1]);
  o.z = bf2f(a[2]) + bf2f(b[2]);
  o.w = bf2f(a[3]) + bf2f(b[3]);
  *(float4*)&out[(size_t)t * DM + c4] = o;
}

// ---------------- launch ----------------
extern "C" void kernel_launch(void* const* d_in, const int* in_sizes, int n_in,
                              void* d_out, int out_size, void* d_ws, size_t ws_size,
                              hipStream_t stream) {
  const float* x   = (const float*)d_in[0];
  const float* Wr  = (const float*)d_in[1];
  const float* fc1 = (const float*)d_in[2];
  const float* fc2 = (const float*)d_in[3];
  const float* A1  = (const float*)d_in[4];
  const float* B1  = (const float*)d_in[5];
  const float* A2  = (const float*)d_in[6];
  const float* B2  = (const float*)d_in[7];
  float* out = (float*)d_out;

  char* ws = (char*)d_ws;
  float* sw1     = (float*)(ws + 0);
  int*   idx1    = (int*)(ws + 512);
  float* sw2     = (float*)(ws + 1024);
  int*   idx2    = (int*)(ws + 1536);
  int*   cnt     = (int*)(ws + 2048);
  float* probsum = (float*)(ws + 2560);
  int*   eidx    = (int*)(ws + 8192);                      // 64 KB
  int*   slots   = (int*)(ws + 8192 + 65536);              // 128 KB
  float* gate    = (float*)(ws + 8192 + 65536 + 131072);   // 512 KB
  int*   perm    = (int*)(ws + 8192 + 65536 + 131072 + 524288); // 512 KB
  u16*   W1p     = (u16*)(ws + 8192 + 65536 + 131072 + 2 * 524288);
  u16*   V1p     = W1p + 1048576;     // packed V1: 8 MB
  u16*   W2p     = V1p + 4194304;     // packed W2: 8 MB
  u16*   V2p     = W2p + 4194304;     // packed V2: 2 MB
  char*  endW    = (char*)(V2p + 1048576);                   // ~22.2 MB
  u16*   u_buf   = (u16*)endW;                               // 49152x256 bf16 = 25.2 MB
  u16*   t_buf   = (u16*)(endW + 25165824);                  // 49152x256 bf16 = 25.2 MB
  u16*   y_buf   = (u16*)(endW + 2 * 25165824);              // 49152x512 bf16 = 50.3 MB
  // total ws use ≈ 123 MB

  zero_kernel<<<3, 256, 0, stream>>>(cnt, probsum);
  compose_meta<<<1, 64, 0, stream>>>(fc1, fc2, sw1, idx1, sw2, idx2);
  build_W1p<<<128, 256, 0, stream>>>(A1, idx1, sw1, W1p);
  build_V1p<<<512, 256, 0, stream>>>(B1, idx1, sw1, V1p);
  build_W2p<<<512, 256, 0, stream>>>(A2, idx2, sw2, W2p);
  build_V2p<<<128, 256, 0, stream>>>(B2, idx2, sw2, V2p);
  router_kernel<<<T_TOK / 64, 256, 0, stream>>>(x, Wr, probsum, eidx, gate);
  scatter_kernel<<<T_TOK / 256, 256, 0, stream>>>(eidx, cnt, perm, slots);
  aux_kernel<<<1, 64, 0, stream>>>(cnt, probsum, out + (out_size - 1));

  k1_u<<<2 * NE * MT_E, 256, 0, stream>>>(x, cnt, perm, W1p, u_buf);
  k23<<<NE * (CAP / 64), 256, 0, stream>>>(u_buf, cnt, V1p, W2p, t_buf);
  k4_y<<<4 * NE * MT_E, 256, 0, stream>>>(t_buf, cnt, perm, gate, V2p, y_buf);
  gather_kernel<<<T_TOK * DM / 4 / 256, 256, 0, stream>>>(y_buf, slots, out);
}

// Round 13
// 340.267 us; speedup vs baseline: 1.3240x; 1.0644x over previous
//
#include <hip/hip_runtime.h>

// ---------------- problem constants ----------------
#define T_TOK 16384
#define DM    512
#define DFF   2048
#define NE    8
#define NP    16
#define KP    4
#define RANK  64
#define KR    256           // KP * RANK
#define EPSF  1e-8f
#define CAP   6144          // per-expert pair capacity (expected ~4096)
#define MT_E  48            // CAP / 128 M-tiles per expert

typedef unsigned short u16;
typedef __bf16 bf16x8 __attribute__((ext_vector_type(8)));
typedef float  f32x4  __attribute__((ext_vector_type(4)));
typedef unsigned short u16x8v __attribute__((ext_vector_type(8)));
typedef unsigned short u16x4v __attribute__((ext_vector_type(4)));

typedef __attribute__((address_space(3))) void as3_void;
typedef __attribute__((address_space(1))) void as1_void;

__device__ __forceinline__ u16 f2bf(float f) {
  return __builtin_bit_cast(u16, (__bf16)f);    // native RTNE cvt (R7)
}
__device__ __forceinline__ float bf2f(u16 v) {
  unsigned int u = ((unsigned int)v) << 16;
  return __builtin_bit_cast(float, u);
}

__device__ __forceinline__ void gl_lds16(const u16* g, u16* l) {
  __builtin_amdgcn_global_load_lds((as1_void*)g, (as3_void*)l, 16, 0, 0);
}

// ---- 3-bit XOR swizzle for 64-col (128 B row-stride) LDS tiles ----
// granule' = granule ^ (row&7); readers XOR col with ((row&7)<<3) == per-lane
// (ln&7)<<3. (R6: st_16x32 1-bit variant is WRONG for this layout.)

// stage 128x64 bf16 tile into LDS, source pre-swizzled (gl_lds dst linear)
__device__ __forceinline__ void stage_tile(const u16* g, int ld, u16* lds_tile, int tid) {
  int row = tid >> 3, cc = tid & 7;
#pragma unroll
  for (int ri = 0; ri < 4; ri++) {
    int rg = ri * 32 + row;
    gl_lds16(g + (size_t)rg * ld + ((cc ^ (rg & 7)) * 8), &lds_tile[rg * 64 + cc * 8]);
  }
}

// ---------------- zero counters ----------------
__global__ void zero_kernel(int* __restrict__ cnt, float* __restrict__ probsum) {
  int i = blockIdx.x * 256 + threadIdx.x;
  if (i < NE) cnt[i] = 0;
  if (i >= NE && i < NE + NE * 64) probsum[i - NE] = 0.f;
}

// ---------------- primitive-bank softmax + top-4 ----------------
__global__ void compose_meta(const float* __restrict__ fc1, const float* __restrict__ fc2,
                             float* __restrict__ sw1, int* __restrict__ idx1,
                             float* __restrict__ sw2, int* __restrict__ idx2) {
  int tid = threadIdx.x;
  if (tid >= 16) return;
  const float* src = (tid < 8) ? fc1 : fc2;
  float* sw = (tid < 8) ? sw1 : sw2;
  int*  idx = (tid < 8) ? idx1 : idx2;
  int e = tid & 7;
  float wv[NP];
  float mx = -1e30f;
  for (int p = 0; p < NP; p++) { wv[p] = src[e * NP + p]; mx = fmaxf(mx, wv[p]); }
  float sum = 0.f;
  for (int p = 0; p < NP; p++) { wv[p] = __expf(wv[p] - mx); sum += wv[p]; }
  float inv = 1.f / sum;
  for (int p = 0; p < NP; p++) wv[p] *= inv;
  float tw[KP]; int ti[KP];
  for (int k = 0; k < KP; k++) {
    int best = 0; float bv = -1.f;
    for (int p = 0; p < NP; p++) if (wv[p] > bv) { bv = wv[p]; best = p; }
    tw[k] = bv; ti[k] = best; wv[best] = -2.f;
  }
  float ts = tw[0] + tw[1] + tw[2] + tw[3];
  float invt = 1.f / (ts + EPSF);
  for (int k = 0; k < KP; k++) {
    sw[e * KP + k] = sqrtf(tw[k] * invt + EPSF);
    idx[e * KP + k] = ti[k];
  }
}

// ---------------- build W1p: fragment-major packed W1 for k1 ---------------
__global__ __launch_bounds__(256) void build_W1p(
    const float* __restrict__ A1, const int* __restrict__ idx1,
    const float* __restrict__ sw1, u16* __restrict__ W1p) {
  __shared__ u16 Ta[2 * 64 * 68];
  int bid = blockIdx.x;
  int k0i = bid & 7, ntile = (bid >> 3) & 1, e = bid >> 4;
  int d0 = k0i * 64;
  int tid = threadIdx.x;
  {
    int kk = tid >> 7, row = (tid >> 1) & 63, half = tid & 1;
    int prim = idx1[e * 4 + ntile * 2 + kk];
    float s = sw1[e * 4 + ntile * 2 + kk];
#pragma unroll
    for (int q = 0; q < 8; q++) {
      int r = half * 32 + q * 4;
      float4 v = *(const float4*)(A1 + ((size_t)prim * DM + d0 + row) * RANK + r);
      u16x4v o;
      o[0] = f2bf(v.x * s); o[1] = f2bf(v.y * s);
      o[2] = f2bf(v.z * s); o[3] = f2bf(v.w * s);
      *(u16x4v*)&Ta[(kk * 64 + row) * 68 + r] = o;
    }
  }
  __syncthreads();
  u16* dst = W1p + ((size_t)(e * 2 + ntile) * 8 + k0i) * 8192;
#pragma unroll
  for (int it = 0; it < 4; it++) {
    int slot = it * 256 + tid;
    int lane = slot & 63, rest = slot >> 6;
    int nt = rest & 3, ks = (rest >> 2) & 1, wn = rest >> 3;
    int ln = lane & 15, quad = lane >> 4;
    int r = nt * 16 + ln;
    int db = ks * 32 + quad * 8;
    u16x8v o;
#pragma unroll
    for (int j = 0; j < 8; j++) o[j] = Ta[(wn * 64 + db + j) * 68 + r];
    *(u16x8v*)&dst[((wn * 8 + ks * 4 + nt) * 64 + lane) * 8] = o;
  }
}

// ---------------- build V1p: fragment-major packed V1 for k23 phase A ------
__global__ __launch_bounds__(256) void build_V1p(
    const float* __restrict__ B1, const int* __restrict__ idx1,
    const float* __restrict__ sw1, u16* __restrict__ V1p) {
  __shared__ u16 Tb[64 * 132];
  int bid = blockIdx.x;
  int p = bid & 3, f0i = (bid >> 2) & 15, e = bid >> 6;
  int prim = idx1[e * 4 + p];
  float s = sw1[e * 4 + p];
  int f0 = f0i * 128;
  int tid = threadIdx.x;
  {
    int r = tid >> 2, fq = (tid & 3) * 32;
#pragma unroll
    for (int q = 0; q < 8; q++) {
      int fl = fq + q * 4;
      float4 v = *(const float4*)(B1 + ((size_t)prim * RANK + r) * DFF + f0 + fl);
      u16x4v o;
      o[0] = f2bf(v.x * s); o[1] = f2bf(v.y * s);
      o[2] = f2bf(v.z * s); o[3] = f2bf(v.w * s);
      *(u16x4v*)&Tb[r * 132 + fl] = o;
    }
  }
  __syncthreads();
  u16* dst = V1p + ((size_t)e << 19) + f0i * 32768 + p * 8192;
#pragma unroll
  for (int it = 0; it < 4; it++) {
    int slot = it * 256 + tid;
    int lane = slot & 63, nt = (slot >> 6) & 1, ks = (slot >> 7) & 1, wv = slot >> 8;
    int ln = lane & 15, quad = lane >> 4;
    int fl = wv * 32 + nt * 16 + ln;
    int r0 = ks * 32 + quad * 8;
    u16x8v o;
#pragma unroll
    for (int j = 0; j < 8; j++) o[j] = Tb[(r0 + j) * 132 + fl];
    *(u16x8v*)&dst[(((wv * 2 + ks) * 2 + nt) * 64 + lane) * 8] = o;
  }
}

// ---------------- build W2p: fragment-major packed W2 for k23 phase B ------
__global__ __launch_bounds__(256) void build_W2p(
    const float* __restrict__ A2, const int* __restrict__ idx2,
    const float* __restrict__ sw2, u16* __restrict__ W2p) {
  __shared__ u16 Ta[2 * 64 * 68];
  int bid = blockIdx.x;
  int c2 = bid & 3, f0i = (bid >> 2) & 15, e = bid >> 6;
  int hh = c2 >> 1, fi = c2 & 1;
  int f0 = f0i * 128 + fi * 64;
  int tid = threadIdx.x;
  {
    int kk = tid >> 7, row = (tid >> 1) & 63, half = tid & 1;
    int prim = idx2[e * 4 + hh * 2 + kk];
    float s = sw2[e * 4 + hh * 2 + kk];
#pragma unroll
    for (int q = 0; q < 8; q++) {
      int r = half * 32 + q * 4;
      float4 v = *(const float4*)(A2 + ((size_t)prim * DFF + f0 + row) * RANK + r);
      u16x4v o;
      o[0] = f2bf(v.x * s); o[1] = f2bf(v.y * s);
      o[2] = f2bf(v.z * s); o[3] = f2bf(v.w * s);
      *(u16x4v*)&Ta[(kk * 64 + row) * 68 + r] = o;
    }
  }
  __syncthreads();
  u16* dst = W2p + ((size_t)e << 19) + f0i * 32768 + c2 * 8192;
#pragma unroll
  for (int it = 0; it < 4; it++) {
    int slot = it * 256 + tid;
    int lane = slot & 63, nt = (slot >> 6) & 1, ks = (slot >> 7) & 1, wv = slot >> 8;
    int ln = lane & 15, quad = lane >> 4;
    int kk = wv >> 1;
    int r = (wv & 1) * 32 + nt * 16 + ln;
    int fb = ks * 32 + quad * 8;
    u16x8v o;
#pragma unroll
    for (int j = 0; j < 8; j++) o[j] = Ta[(kk * 64 + fb + j) * 68 + r];
    *(u16x8v*)&dst[(((wv * 2 + ks) * 2 + nt) * 64 + lane) * 8] = o;
  }
}

// ---------------- build V2p: fragment-major packed V2 for k4 ---------------
__global__ __launch_bounds__(256) void build_V2p(
    const float* __restrict__ B2, const int* __restrict__ idx2,
    const float* __restrict__ sw2, u16* __restrict__ V2p) {
  __shared__ u16 Tb[64 * 132];
  int bid = blockIdx.x;
  int k0i = bid & 3, ntile = (bid >> 2) & 3, e = bid >> 4;
  int prim = idx2[e * 4 + k0i];
  float s = sw2[e * 4 + k0i];
  int tid = threadIdx.x;
  {
    int r = tid >> 2, dq = (tid & 3) * 32;
#pragma unroll
    for (int q = 0; q < 8; q++) {
      int dd = dq + q * 4;
      float4 v = *(const float4*)(B2 + ((size_t)prim * RANK + r) * DM + ntile * 128 + dd);
      u16x4v o;
      o[0] = f2bf(v.x * s); o[1] = f2bf(v.y * s);
      o[2] = f2bf(v.z * s); o[3] = f2bf(v.w * s);
      *(u16x4v*)&Tb[r * 132 + dd] = o;
    }
  }
  __syncthreads();
  u16* dst = V2p + ((size_t)(e * 4 + ntile) * 4 + k0i) * 8192;
#pragma unroll
  for (int it = 0; it < 4; it++) {
    int slot = it * 256 + tid;
    int lane = slot & 63, rest = slot >> 6;
    int nt = rest & 3, ks = (rest >> 2) & 1, wn = rest >> 3;
    int ln = lane & 15, quad = lane >> 4;
    int dd = wn * 64 + nt * 16 + ln;
    int r0 = ks * 32 + quad * 8;
    u16x8v o;
#pragma unroll
    for (int j = 0; j < 8; j++) o[j] = Tb[(r0 + j) * 132 + dd];
    *(u16x8v*)&dst[((wn * 8 + ks * 4 + nt) * 64 + lane) * 8] = o;
  }
}

// ---------------- router, token-per-lane (k-split 4) ----------------
__global__ __launch_bounds__(256) void router_kernel(
    const float* __restrict__ x, const float* __restrict__ Wr,
    float* __restrict__ probsum, int* __restrict__ eidx,
    float* __restrict__ gate) {
  __shared__ float wr_s[NE * 4 * 132];
  __shared__ float ps_s[NE];
  int tid = threadIdx.x;
  if (tid < NE) ps_s[tid] = 0.f;
  for (int i = tid; i < NE * DM; i += 256) {
    int e = i >> 9, k = i & 511;
    wr_s[(e * 4 + (k >> 7)) * 132 + (k & 127)] = Wr[i];
  }
  __syncthreads();
  int lane = tid & 63, wv = tid >> 6;
  int tl = lane & 15, sl = lane >> 4;
  int t = blockIdx.x * 64 + wv * 16 + tl;
  const float* xp = x + (size_t)t * DM + sl * 128;
  const float* wp = &wr_s[sl * 132];
  float acc[NE];
#pragma unroll
  for (int e = 0; e < NE; e++) acc[e] = 0.f;
  for (int c = 0; c < 32; c++) {
    float4 xv = *(const float4*)(xp + c * 4);
#pragma unroll
    for (int e = 0; e < NE; e++) {
      float4 w4 = *(const float4*)(wp + e * 4 * 132 + c * 4);
      acc[e] += xv.x * w4.x + xv.y * w4.y + xv.z * w4.z + xv.w * w4.w;
    }
  }
#pragma unroll
  for (int e = 0; e < NE; e++) {
    acc[e] += __shfl_xor(acc[e], 16, 64);
    acc[e] += __shfl_xor(acc[e], 32, 64);
  }
  if (sl == 0) {
    float mx = acc[0];
#pragma unroll
    for (int e = 1; e < NE; e++) mx = fmaxf(mx, acc[e]);
    float pe[NE]; float sum = 0.f;
#pragma unroll
    for (int e = 0; e < NE; e++) { pe[e] = __expf(acc[e] - mx); sum += pe[e]; }
    float inv = 1.f / sum;
#pragma unroll
    for (int e = 0; e < NE; e++) pe[e] *= inv;
    int i0 = 0;
#pragma unroll
    for (int e = 1; e < NE; e++) if (pe[e] > pe[i0]) i0 = e;
    int i1 = (i0 == 0) ? 1 : 0;
#pragma unroll
    for (int e = 0; e < NE; e++) if (e != i0 && pe[e] > pe[i1]) i1 = e;
    float p0 = pe[i0], p1 = pe[i1];
    float gd = 1.f / (p0 + p1 + EPSF);
    eidx[t] = i0 | (i1 << 3);
    gate[i0 * T_TOK + t] = p0 * gd;
    gate[i1 * T_TOK + t] = p1 * gd;
#pragma unroll
    for (int e = 0; e < NE; e++) atomicAdd(&ps_s[e], pe[e]);
  }
  __syncthreads();
  if (tid < NE) atomicAdd(&probsum[tid * 64 + (blockIdx.x & 63)], ps_s[tid]);
}

// ---------------- scatter (block-aggregated cnt) + per-token slot pairs ----------
__global__ void scatter_kernel(const int* __restrict__ eidx,
                               int* __restrict__ cnt, int* __restrict__ perm,
                               int* __restrict__ slots) {
  __shared__ int hist[NE], base[NE];
  int tid = threadIdx.x;
  if (tid < NE) hist[tid] = 0;
  __syncthreads();
  int t = blockIdx.x * 256 + tid;
  int pk = eidx[t];
  int e0 = pk & 7, e1 = (pk >> 3) & 7;
  int p0 = atomicAdd(&hist[e0], 1);
  int p1 = atomicAdd(&hist[e1], 1);
  __syncthreads();
  if (tid < NE) base[tid] = atomicAdd(&cnt[tid], hist[tid]);
  __syncthreads();
  int g0 = base[e0] + p0; if (g0 >= CAP) g0 = CAP - 1;
  int g1 = base[e1] + p1; if (g1 >= CAP) g1 = CAP - 1;
  perm[e0 * T_TOK + g0] = t;
  perm[e1 * T_TOK + g1] = t;
  slots[t * 2]     = e0 * CAP + g0;
  slots[t * 2 + 1] = e1 * CAP + g1;
}

// ---------------- aux loss (one wave) ----------------
__global__ void aux_kernel(const int* __restrict__ cnt, const float* __restrict__ probsum,
                           float* __restrict__ aux_out) {
  int lane = threadIdx.x;
  if (lane >= 64) return;
  float s[NE];
#pragma unroll
  for (int e = 0; e < NE; e++) {
    float v = probsum[e * 64 + lane];
#pragma unroll
    for (int off = 32; off > 0; off >>= 1) v += __shfl_xor(v, off, 64);
    s[e] = v;
  }
  if (lane == 0) {
    float c[NE]; float cs = 0.f;
    for (int e = 0; e < NE; e++) { c[e] = (float)cnt[e]; cs += c[e]; }
    float aux = 0.f;
    for (int e = 0; e < NE; e++)
      aux += (c[e] / (cs + EPSF)) * (s[e] / (float)T_TOK);
    *aux_out = (float)NE * aux;
  }
}

// ================= FFN pipeline =================
// All FFN kernels decode expert = bid & 7 (XCD affinity, R3-confirmed).
// R8/R9: fragment-packed B direct global->register.
// R13: all blocks of an expert previously read the IDENTICAL weight stream in
// lockstep -> same-line L2 channel serialization (measured ~11 B/cyc/CU vs
// ~60 available). Stagger each block's weight-chunk start phase by its mt
// index so concurrent requests hit different lines/channels. Accumulation
// order changes only fp32 summation order.

// K1 v3: u[slot,256] = bf16( gather(x) @ A1c ), B from packed W1p, k staggered.
__global__ __launch_bounds__(256) void k1_u(
    const float* __restrict__ x, const int* __restrict__ cnt,
    const int* __restrict__ perm, const u16* __restrict__ W1p,
    u16* __restrict__ u) {
  __shared__ __align__(16) u16 As[8192];
  __shared__ int tok_s[128];
  int bid = blockIdx.x;
  int e = bid & 7;
  int r0 = bid >> 3;
  int ntile = r0 & 1, mt = r0 >> 1;
  int m0 = mt << 7;
  int cntE = cnt[e];
  if (m0 >= cntE) return;
  int tid = threadIdx.x;
  if (tid < 128) {
    int mm = m0 + tid; if (mm > cntE - 1) mm = cntE - 1;
    tok_s[tid] = perm[e * T_TOK + mm];
  }
  __syncthreads();
  int wv = tid >> 6, lane = tid & 63;
  int wm = wv >> 1, wn = wv & 1, ln = lane & 15, quad = lane >> 4;
  int sw = (ln & 7) << 3;
  const u16* Wbase = W1p + ((size_t)(e * 2 + ntile) * 8) * 8192 + (wn * 8 * 64 + lane) * 8;
  int kst = mt & 7;                        // stagger phase
  f32x4 acc[4][4];
#pragma unroll
  for (int a = 0; a < 4; a++)
#pragma unroll
    for (int b = 0; b < 4; b++) acc[a][b] = (f32x4){0.f, 0.f, 0.f, 0.f};
  for (int kk = 0; kk < 8; kk++) {
    int k0i = (kk + kst) & 7;
    // B fragments (global, L2-resident) — issue before As stage/barrier
    bf16x8 bf[2][4];
    const u16* Wf = Wbase + (size_t)k0i * 8192;
#pragma unroll
    for (int ks = 0; ks < 2; ks++)
#pragma unroll
      for (int nt = 0; nt < 4; nt++)
        bf[ks][nt] = *(const bf16x8*)&Wf[(ks * 4 + nt) * 512];
    // As stage: gather x rows, cvt, swizzled write
    for (int i = tid; i < 2048; i += 256) {
      int row = i >> 4, c4 = i & 15;
      float4 v = *(const float4*)(x + (size_t)tok_s[row] * DM + k0i * 64 + c4 * 4);
      u16x4v o; o[0] = f2bf(v.x); o[1] = f2bf(v.y); o[2] = f2bf(v.z); o[3] = f2bf(v.w);
      *(u16x4v*)&As[row * 64 + ((c4 * 4) ^ ((row & 7) << 3))] = o;
    }
    __syncthreads();
#pragma unroll
    for (int ks = 0; ks < 2; ks++) {
      bf16x8 af[4];
      int co = (ks * 32 + quad * 8) ^ sw;
#pragma unroll
      for (int mt2 = 0; mt2 < 4; mt2++)
        af[mt2] = *(const bf16x8*)&As[(wm * 64 + mt2 * 16 + ln) * 64 + co];
      __builtin_amdgcn_s_setprio(1);
#pragma unroll
      for (int mt2 = 0; mt2 < 4; mt2++)
#pragma unroll
        for (int nt = 0; nt < 4; nt++)
          acc[mt2][nt] = __builtin_amdgcn_mfma_f32_16x16x32_bf16(af[mt2], bf[ks][nt], acc[mt2][nt], 0, 0, 0);
      __builtin_amdgcn_s_setprio(0);
    }
    __syncthreads();
  }
  int slot0 = e * CAP + m0;
#pragma unroll
  for (int mt2 = 0; mt2 < 4; mt2++)
#pragma unroll
    for (int nt = 0; nt < 4; nt++)
#pragma unroll
      for (int r = 0; r < 4; r++) {
        int row = wm * 64 + mt2 * 16 + quad * 4 + r;
        int col = ntile * 128 + wn * 64 + nt * 16 + ln;
        u[(size_t)(slot0 + row) * KR + col] = f2bf(acc[mt2][nt][r]);
      }
}

// K23 v13: = v12 (half-register u) + f0i phase-stagger (mt & 15).
// LDS = Us16 16K + Hs 16K = 32 KB; VGPR 128, no spill (R12-verified).
__global__ __launch_bounds__(256, 2) void k23(
    const u16* __restrict__ u, const int* __restrict__ cnt,
    const u16* __restrict__ V1p, const u16* __restrict__ W2p,
    u16* __restrict__ t) {
  __shared__ __align__(16) u16 Us16[64 * 128];    // 16 KB: u cols 128..255 (swizzled)
  __shared__ __align__(16) u16 Hs[64 * 128];      // 16 KB gelu tile (swizzled)
  int bid = blockIdx.x;
  int e = bid & 7, mt = bid >> 3;
  int m0 = mt << 6;
  int cntE = cnt[e];
  if (m0 >= cntE) return;
  int tid = threadIdx.x;
  int slot0 = e * CAP + m0;
  const u16* ub = u + (size_t)slot0 * KR;

  // ---- prologue: stage u cols 128..255 into Us16 (src pre-swizzled) ----
#pragma unroll
  for (int r = 0; r < 4; r++) {
    int i = r * 256 + tid;                 // 16 B chunk id, 0..1023
    int row = i >> 4, cc = i & 15;
    gl_lds16(ub + (size_t)row * 256 + 128 + ((cc ^ (row & 7)) * 8), &Us16[i * 8]);
  }

  int wv = tid >> 6, lane = tid & 63;
  int ln = lane & 15, quad = lane >> 4;
  int sw = (ln & 7) << 3;

  // ---- u cols 0..127 -> registers: ureg[p][ks][m], p in {0,1} (64 VGPR) ----
  bf16x8 ureg[2][2][4];
#pragma unroll
  for (int p = 0; p < 2; p++)
#pragma unroll
    for (int ks = 0; ks < 2; ks++)
#pragma unroll
      for (int m = 0; m < 4; m++)
        ureg[p][ks][m] = *(const bf16x8*)&ub[(size_t)(m * 16 + ln) * KR + p * 64 + ks * 32 + quad * 8];

  __syncthreads();                          // drains gl_lds; Us16 ready

  // packed weight bases: [e][f0i][p|c2][wv][ks][nt][lane][8]
  const u16* V1w = V1p + ((size_t)e << 19) + wv * 2048 + lane * 8;
  const u16* W2w = W2p + ((size_t)e << 19) + wv * 2048 + lane * 8;

  f32x4 tacc[4][4];   // [m][hh*2+nt] ; wave wv owns t cols hh*128 + wv*32 + nt*16 + ln
#pragma unroll
  for (int a = 0; a < 4; a++)
#pragma unroll
    for (int b = 0; b < 4; b++) tacc[a][b] = (f32x4){0.f, 0.f, 0.f, 0.f};
  f32x4 hacc[4][2];

  int fst = mt & 15;                        // stagger phase
  for (int ii = 0; ii < 16; ii++) {
    int f0i = (ii + fst) & 15;
    const u16* V1f = V1w + f0i * 32768;
    const u16* W2f = W2w + f0i * 32768;
    // ---- phase A: h(64x128) += u @ V1 (p 0-1 from regs, p 2-3 from Us16) ----
#pragma unroll
    for (int p = 0; p < 4; p++) {
      bf16x8 bf[2][2];
#pragma unroll
      for (int ks = 0; ks < 2; ks++)
#pragma unroll
        for (int nt = 0; nt < 2; nt++)
          bf[ks][nt] = *(const bf16x8*)&V1f[p * 8192 + (ks * 2 + nt) * 512];
      if (p == 0) {
#pragma unroll
        for (int a = 0; a < 4; a++)
#pragma unroll
          for (int b = 0; b < 2; b++) hacc[a][b] = (f32x4){0.f, 0.f, 0.f, 0.f};
      }
      if (p < 2) {
        __builtin_amdgcn_s_setprio(1);
#pragma unroll
        for (int ks = 0; ks < 2; ks++)
#pragma unroll
          for (int m = 0; m < 4; m++)
#pragma unroll
            for (int nt = 0; nt < 2; nt++)
              hacc[m][nt] = __builtin_amdgcn_mfma_f32_16x16x32_bf16(ureg[p][ks][m], bf[ks][nt], hacc[m][nt], 0, 0, 0);
        __builtin_amdgcn_s_setprio(0);
      } else {
        bf16x8 af[2][4];
#pragma unroll
        for (int ks = 0; ks < 2; ks++) {
          int cu = ((p - 2) * 64 + ks * 32 + quad * 8) ^ sw;
#pragma unroll
          for (int m = 0; m < 4; m++)
            af[ks][m] = *(const bf16x8*)&Us16[((m * 16 + ln) << 7) + cu];
        }
        __builtin_amdgcn_s_setprio(1);
#pragma unroll
        for (int ks = 0; ks < 2; ks++)
#pragma unroll
          for (int m = 0; m < 4; m++)
#pragma unroll
            for (int nt = 0; nt < 2; nt++)
              hacc[m][nt] = __builtin_amdgcn_mfma_f32_16x16x32_bf16(af[ks][m], bf[ks][nt], hacc[m][nt], 0, 0, 0);
        __builtin_amdgcn_s_setprio(0);
      }
    }
    // ---- barrier 1: all waves done reading PREVIOUS iteration's Hs ----
    __syncthreads();
    // gelu -> Hs (swizzled write matches swizzled read)
#pragma unroll
    for (int m = 0; m < 4; m++)
#pragma unroll
      for (int nt = 0; nt < 2; nt++)
#pragma unroll
        for (int r = 0; r < 4; r++) {
          int row = m * 16 + quad * 4 + r;
          int col = wv * 32 + nt * 16 + ln;
          float v = hacc[m][nt][r];
          float s = 1.f / (1.f + __expf(-1.702f * v));
          Hs[(row << 7) + (col ^ ((row & 7) << 3))] = f2bf(v * s);
        }
    // ---- barrier 2: publish Hs ----
    __syncthreads();
    // ---- phase B: tacc += gelu(h) @ W2 (4 chunks, NO barriers) ----
#pragma unroll
    for (int c2 = 0; c2 < 4; c2++) {
      const int hh = c2 >> 1, fi = c2 & 1;
      bf16x8 bf[2][2], af[2][4];
#pragma unroll
      for (int ks = 0; ks < 2; ks++)
#pragma unroll
        for (int nt = 0; nt < 2; nt++)
          bf[ks][nt] = *(const bf16x8*)&W2f[c2 * 8192 + (ks * 2 + nt) * 512];
#pragma unroll
      for (int ks = 0; ks < 2; ks++) {
        int ch = (fi * 64 + ks * 32 + quad * 8) ^ sw;
#pragma unroll
        for (int m = 0; m < 4; m++)
          af[ks][m] = *(const bf16x8*)&Hs[((m * 16 + ln) << 7) + ch];
      }
      __builtin_amdgcn_s_setprio(1);
#pragma unroll
      for (int ks = 0; ks < 2; ks++)
#pragma unroll
        for (int m = 0; m < 4; m++)
#pragma unroll
          for (int nt = 0; nt < 2; nt++)
            tacc[m][hh * 2 + nt] = __builtin_amdgcn_mfma_f32_16x16x32_bf16(af[ks][m], bf[ks][nt], tacc[m][hh * 2 + nt], 0, 0, 0);
      __builtin_amdgcn_s_setprio(0);
    }
  }
  // epilogue: t (bf16, written once — no RMW)
#pragma unroll
  for (int m = 0; m < 4; m++)
#pragma unroll
    for (int hh = 0; hh < 2; hh++)
#pragma unroll
      for (int nt = 0; nt < 2; nt++)
#pragma unroll
        for (int r = 0; r < 4; r++) {
          int row = m * 16 + quad * 4 + r;
          int col = hh * 128 + wv * 32 + nt * 16 + ln;
          t[(size_t)(slot0 + row) * KR + col] = f2bf(tacc[m][hh * 2 + nt][r]);
        }
}

// K4 v3: y[slot, 512] = gate * (t @ B2c), B from packed V2p, k staggered.
__global__ __launch_bounds__(256) void k4_y(
    const u16* __restrict__ t, const int* __restrict__ cnt,
    const int* __restrict__ perm, const float* __restrict__ gate,
    const u16* __restrict__ V2p, u16* __restrict__ y) {
  __shared__ __align__(16) u16 As[8192];
  __shared__ float g_s[128];
  int bid = blockIdx.x;
  int e = bid & 7;
  int r0 = bid >> 3;
  int ntile = r0 & 3, mt = r0 >> 2;
  int m0 = mt << 7;
  int cntE = cnt[e];
  if (m0 >= cntE) return;
  int tid = threadIdx.x;
  if (tid < 128) {
    int mm = m0 + tid; if (mm > cntE - 1) mm = cntE - 1;
    int tk = perm[e * T_TOK + mm];
    g_s[tid] = gate[e * T_TOK + tk];
  }
  __syncthreads();
  int slot0 = e * CAP + m0;
  const u16* Abase = t + (size_t)slot0 * KR;
  int wv = tid >> 6, lane = tid & 63;
  int wm = wv >> 1, wn = wv & 1, ln = lane & 15, quad = lane >> 4;
  int sw = (ln & 7) << 3;
  const u16* Wbase = V2p + ((size_t)(e * 4 + ntile) * 4) * 8192 + (wn * 8 * 64 + lane) * 8;
  int kst = mt & 3;                        // stagger phase
  f32x4 acc[4][4];
#pragma unroll
  for (int a = 0; a < 4; a++)
#pragma unroll
    for (int b = 0; b < 4; b++) acc[a][b] = (f32x4){0.f, 0.f, 0.f, 0.f};
  for (int kk = 0; kk < 4; kk++) {
    int k0i = (kk + kst) & 3;
    // B fragments (global, L2) — issue before As stage/barrier
    bf16x8 bf[2][4];
    const u16* Wf = Wbase + (size_t)k0i * 8192;
#pragma unroll
    for (int ks = 0; ks < 2; ks++)
#pragma unroll
      for (int nt = 0; nt < 4; nt++)
        bf[ks][nt] = *(const bf16x8*)&Wf[(ks * 4 + nt) * 512];
    stage_tile(Abase + k0i * 64, KR, As, tid);
    __syncthreads();
#pragma unroll
    for (int ks = 0; ks < 2; ks++) {
      bf16x8 af[4];
      int co = (ks * 32 + quad * 8) ^ sw;
#pragma unroll
      for (int mt2 = 0; mt2 < 4; mt2++)
        af[mt2] = *(const bf16x8*)&As[(wm * 64 + mt2 * 16 + ln) * 64 + co];
      __builtin_amdgcn_s_setprio(1);
#pragma unroll
      for (int mt2 = 0; mt2 < 4; mt2++)
#pragma unroll
        for (int nt = 0; nt < 4; nt++)
          acc[mt2][nt] = __builtin_amdgcn_mfma_f32_16x16x32_bf16(af[mt2], bf[ks][nt], acc[mt2][nt], 0, 0, 0);
      __builtin_amdgcn_s_setprio(0);
    }
    __syncthreads();
  }
#pragma unroll
  for (int mt2 = 0; mt2 < 4; mt2++)
#pragma unroll
    for (int nt = 0; nt < 4; nt++)
#pragma unroll
      for (int r = 0; r < 4; r++) {
        int row = wm * 64 + mt2 * 16 + quad * 4 + r;
        int col = ntile * 128 + wn * 64 + nt * 16 + ln;
        y[(size_t)(slot0 + row) * DM + col] = f2bf(acc[mt2][nt][r] * g_s[row]);
      }
}

// gather: out[t] = y[slotA] + y[slotB]
__global__ void gather_kernel(const u16* __restrict__ y, const int* __restrict__ slots,
                              float* __restrict__ out) {
  int idx = blockIdx.x * 256 + threadIdx.x;
  int t = idx >> 7, c4 = (idx & 127) * 4;
  int sA = slots[t * 2], sB = slots[t * 2 + 1];
  u16x4v a = *(const u16x4v*)&y[(size_t)sA * DM + c4];
  u16x4v b = *(const u16x4v*)&y[(size_t)sB * DM + c4];
  float4 o;
  o.x = bf2f(a[0]) + bf2f(b[0]);
  o.y = bf2f(a[1]) + bf2f(b[1]);
  o.z = bf2f(a[2]) + bf2f(b[2]);
  o.w = bf2f(a[3]) + bf2f(b[3]);
  *(float4*)&out[(size_t)t * DM + c4] = o;
}

// ---------------- launch ----------------
extern "C" void kernel_launch(void* const* d_in, const int* in_sizes, int n_in,
                              void* d_out, int out_size, void* d_ws, size_t ws_size,
                              hipStream_t stream) {
  const float* x   = (const float*)d_in[0];
  const float* Wr  = (const float*)d_in[1];
  const float* fc1 = (const float*)d_in[2];
  const float* fc2 = (const float*)d_in[3];
  const float* A1  = (const float*)d_in[4];
  const float* B1  = (const float*)d_in[5];
  const float* A2  = (const float*)d_in[6];
  const float* B2  = (const float*)d_in[7];
  float* out = (float*)d_out;

  char* ws = (char*)d_ws;
  float* sw1     = (float*)(ws + 0);
  int*   idx1    = (int*)(ws + 512);
  float* sw2     = (float*)(ws + 1024);
  int*   idx2    = (int*)(ws + 1536);
  int*   cnt     = (int*)(ws + 2048);
  float* probsum = (float*)(ws + 2560);
  int*   eidx    = (int*)(ws + 8192);                      // 64 KB
  int*   slots   = (int*)(ws + 8192 + 65536);              // 128 KB
  float* gate    = (float*)(ws + 8192 + 65536 + 131072);   // 512 KB
  int*   perm    = (int*)(ws + 8192 + 65536 + 131072 + 524288); // 512 KB
  u16*   W1p     = (u16*)(ws + 8192 + 65536 + 131072 + 2 * 524288);
  u16*   V1p     = W1p + 1048576;     // packed V1: 8 MB
  u16*   W2p     = V1p + 4194304;     // packed W2: 8 MB
  u16*   V2p     = W2p + 4194304;     // packed V2: 2 MB
  char*  endW    = (char*)(V2p + 1048576);                   // ~22.2 MB
  u16*   u_buf   = (u16*)endW;                               // 49152x256 bf16 = 25.2 MB
  u16*   t_buf   = (u16*)(endW + 25165824);                  // 49152x256 bf16 = 25.2 MB
  u16*   y_buf   = (u16*)(endW + 2 * 25165824);              // 49152x512 bf16 = 50.3 MB
  // total ws use ≈ 123 MB

  zero_kernel<<<3, 256, 0, stream>>>(cnt, probsum);
  compose_meta<<<1, 64, 0, stream>>>(fc1, fc2, sw1, idx1, sw2, idx2);
  build_W1p<<<128, 256, 0, stream>>>(A1, idx1, sw1, W1p);
  build_V1p<<<512, 256, 0, stream>>>(B1, idx1, sw1, V1p);
  build_W2p<<<512, 256, 0, stream>>>(A2, idx2, sw2, W2p);
  build_V2p<<<128, 256, 0, stream>>>(B2, idx2, sw2, V2p);
  router_kernel<<<T_TOK / 64, 256, 0, stream>>>(x, Wr, probsum, eidx, gate);
  scatter_kernel<<<T_TOK / 256, 256, 0, stream>>>(eidx, cnt, perm, slots);
  aux_kernel<<<1, 64, 0, stream>>>(cnt, probsum, out + (out_size - 1));

  k1_u<<<2 * NE * MT_E, 256, 0, stream>>>(x, cnt, perm, W1p, u_buf);
  k23<<<NE * (CAP / 64), 256, 0, stream>>>(u_buf, cnt, V1p, W2p, t_buf);
  k4_y<<<4 * NE * MT_E, 256, 0, stream>>>(t_buf, cnt, perm, gate, V2p, y_buf);
  gather_kernel<<<T_TOK * DM / 4 / 256, 256, 0, stream>>>(y_buf, slots, out);
}